// Round 1
// baseline (9586.688 us; speedup 1.0000x reference)
//
#include <hip/hip_runtime.h>
#include <math.h>

// Problem constants (match reference setup_inputs)
#define NN 50000
#define EE 150000
#define HH 128
#define HALF 64
#define LL 15

static __device__ __forceinline__ float gelu_f(float x) {
    // exact (erf) GELU, matches jax.nn.gelu(approximate=False)
    return 0.5f * x * (1.0f + erff(x * 0.70710678118654752440f));
}

// acc[i][j] += sum_{kk<KC} A[(r0+i)*lda + kk] * W[kk*128 + c0 + j]
template <int KC>
static __device__ __forceinline__ void gemm_chunk(const float* A, int lda,
                                                  const float* W,
                                                  int r0, int c0, float acc[4][4]) {
#pragma unroll
    for (int kk = 0; kk < KC; kk += 4) {
        float4 a[4];
        float4 w[4];
#pragma unroll
        for (int i = 0; i < 4; ++i) a[i] = *(const float4*)(A + (r0 + i) * lda + kk);
#pragma unroll
        for (int m = 0; m < 4; ++m) w[m] = *(const float4*)(W + (kk + m) * 128 + c0);
#pragma unroll
        for (int i = 0; i < 4; ++i) {
            float am[4] = {a[i].x, a[i].y, a[i].z, a[i].w};
#pragma unroll
            for (int m = 0; m < 4; ++m) {
                acc[i][0] = fmaf(am[m], w[m].x, acc[i][0]);
                acc[i][1] = fmaf(am[m], w[m].y, acc[i][1]);
                acc[i][2] = fmaf(am[m], w[m].z, acc[i][2]);
                acc[i][3] = fmaf(am[m], w[m].w, acc[i][3]);
            }
        }
    }
}

// h[(r0+i)*128 + c0+j] = gelu(acc[i][j] + b[c0+j]); acc reset to 0
static __device__ __forceinline__ void bias_gelu_store(float acc[4][4],
                                                       const float* __restrict__ b,
                                                       float* h, int r0, int c0) {
    float4 bb = *(const float4*)(b + c0);
    float bv[4] = {bb.x, bb.y, bb.z, bb.w};
#pragma unroll
    for (int i = 0; i < 4; ++i) {
        float4 o;
        o.x = gelu_f(acc[i][0] + bv[0]);
        o.y = gelu_f(acc[i][1] + bv[1]);
        o.z = gelu_f(acc[i][2] + bv[2]);
        o.w = gelu_f(acc[i][3] + bv[3]);
        *(float4*)(h + (r0 + i) * 128 + c0) = o;
#pragma unroll
        for (int j = 0; j < 4; ++j) acc[i][j] = 0.f;
    }
}

// LayerNorm over the 128-wide row held by the 32 consecutive lanes sharing ty.
// vals[i][j] = (acc[i][j]+b) normalized * g + beta
static __device__ __forceinline__ void ln_block(float acc[4][4],
                                                const float* __restrict__ b,
                                                const float* __restrict__ g,
                                                const float* __restrict__ beta,
                                                int c0, float vals[4][4]) {
    float4 bb = *(const float4*)(b + c0);
    float bv[4] = {bb.x, bb.y, bb.z, bb.w};
    float4 gg = *(const float4*)(g + c0);
    float gv[4] = {gg.x, gg.y, gg.z, gg.w};
    float4 bt = *(const float4*)(beta + c0);
    float btv[4] = {bt.x, bt.y, bt.z, bt.w};
#pragma unroll
    for (int i = 0; i < 4; ++i) {
        float v[4];
#pragma unroll
        for (int j = 0; j < 4; ++j) v[j] = acc[i][j] + bv[j];
        float s = v[0] + v[1] + v[2] + v[3];
        float ss = v[0] * v[0] + v[1] * v[1] + v[2] * v[2] + v[3] * v[3];
        // reduce across the 32 lanes sharing ty (masks < 32 stay in-group)
#pragma unroll
        for (int m = 1; m < 32; m <<= 1) {
            s += __shfl_xor(s, m, 64);
            ss += __shfl_xor(ss, m, 64);
        }
        float mean = s * (1.0f / 128.0f);
        float var = ss * (1.0f / 128.0f) - mean * mean;
        float rstd = rsqrtf(var + 1e-5f);
#pragma unroll
        for (int j = 0; j < 4; ++j) vals[i][j] = (v[j] - mean) * rstd * gv[j] + btv[j];
    }
}

// ---------------- Encoder: [rows,16] -> MLP(16,128,128,128) -> LN -> out [rows,128]
__global__ __launch_bounds__(256) void enc_kernel(
    const float* __restrict__ in, float* __restrict__ out,
    const float* __restrict__ W1, const float* __restrict__ b1,
    const float* __restrict__ W2, const float* __restrict__ b2,
    const float* __restrict__ W3, const float* __restrict__ b3,
    const float* __restrict__ g, const float* __restrict__ beta, int nrows) {
    __shared__ __align__(16) float Ast[32 * 16];
    __shared__ __align__(16) float Wt[32 * 128];
    __shared__ __align__(16) float h1[32 * 128];
    __shared__ __align__(16) float h2[32 * 128];
    int t = threadIdx.x;
    int tx = t & 31, ty = t >> 5;
    int r0 = ty * 4, c0 = tx * 4;
    int n0 = blockIdx.x * 32;

    if (t < 128) {
        int row = t >> 2, fc = t & 3;
        int rid = min(n0 + row, nrows - 1);
        *(float4*)(Ast + row * 16 + fc * 4) = *(const float4*)(in + (size_t)rid * 16 + fc * 4);
    }
    for (int q = t; q < 512; q += 256)
        *(float4*)(Wt + q * 4) = *(const float4*)(W1 + (size_t)q * 4);
    __syncthreads();
    float acc[4][4] = {};
    gemm_chunk<16>(Ast, 16, Wt, r0, c0, acc);
    __syncthreads();
    bias_gelu_store(acc, b1, h1, r0, c0);
    for (int c = 0; c < 4; ++c) {
        for (int q = t; q < 1024; q += 256)
            *(float4*)(Wt + q * 4) = *(const float4*)(W2 + (size_t)c * 32 * 128 + q * 4);
        __syncthreads();
        gemm_chunk<32>(h1 + c * 32, 128, Wt, r0, c0, acc);
        __syncthreads();
    }
    bias_gelu_store(acc, b2, h2, r0, c0);
    for (int c = 0; c < 4; ++c) {
        for (int q = t; q < 1024; q += 256)
            *(float4*)(Wt + q * 4) = *(const float4*)(W3 + (size_t)c * 32 * 128 + q * 4);
        __syncthreads();
        gemm_chunk<32>(h2 + c * 32, 128, Wt, r0, c0, acc);
        __syncthreads();
    }
    float vals[4][4];
    ln_block(acc, b3, g, beta, c0, vals);
#pragma unroll
    for (int i = 0; i < 4; ++i) {
        int rid = n0 + r0 + i;
        if (rid < nrows) {
            float4 o = {vals[i][0], vals[i][1], vals[i][2], vals[i][3]};
            *(float4*)(out + (size_t)rid * 128 + c0) = o;
        }
    }
}

// ---------------- Edge block: concat(x[s],x[r],e) -> MLP(384,...) -> LN -> e+=new, scatter agg
__global__ __launch_bounds__(256) void edge_block_kernel(
    const float* __restrict__ x, float* __restrict__ e,
    const int* __restrict__ senders, const int* __restrict__ receivers,
    const float* __restrict__ W1, const float* __restrict__ b1,
    const float* __restrict__ W2, const float* __restrict__ b2,
    const float* __restrict__ W3, const float* __restrict__ b3,
    const float* __restrict__ g, const float* __restrict__ beta,
    float* __restrict__ agg, int E_) {
    __shared__ __align__(16) float Ast[32 * 32];
    __shared__ __align__(16) float Wt[32 * 128];
    __shared__ __align__(16) float h1[32 * 128];
    __shared__ __align__(16) float h2[32 * 128];
    __shared__ int sh_s[32], sh_r[32];
    int t = threadIdx.x;
    int tx = t & 31, ty = t >> 5;
    int r0 = ty * 4, c0 = tx * 4;
    int e0 = blockIdx.x * 32;
    if (t < 32) {
        int eid = min(e0 + t, E_ - 1);
        sh_s[t] = senders[eid];
        sh_r[t] = receivers[eid];
    }
    __syncthreads();
    float acc[4][4] = {};
    // MLP1: K=384 in 12 chunks of 32 (0..3 sender-x, 4..7 receiver-x, 8..11 e)
    for (int c = 0; c < 12; ++c) {
        {
            int row = t >> 3, fc = t & 7;
            int eid = min(e0 + row, E_ - 1);
            const float* src;
            if (c < 4)      src = x + (size_t)sh_s[row] * 128 + c * 32;
            else if (c < 8) src = x + (size_t)sh_r[row] * 128 + (c - 4) * 32;
            else            src = e + (size_t)eid * 128 + (c - 8) * 32;
            *(float4*)(Ast + row * 32 + fc * 4) = *(const float4*)(src + fc * 4);
        }
        for (int q = t; q < 1024; q += 256)
            *(float4*)(Wt + q * 4) = *(const float4*)(W1 + (size_t)c * 32 * 128 + q * 4);
        __syncthreads();
        gemm_chunk<32>(Ast, 32, Wt, r0, c0, acc);
        __syncthreads();
    }
    bias_gelu_store(acc, b1, h1, r0, c0);
    for (int c = 0; c < 4; ++c) {
        for (int q = t; q < 1024; q += 256)
            *(float4*)(Wt + q * 4) = *(const float4*)(W2 + (size_t)c * 32 * 128 + q * 4);
        __syncthreads();
        gemm_chunk<32>(h1 + c * 32, 128, Wt, r0, c0, acc);
        __syncthreads();
    }
    bias_gelu_store(acc, b2, h2, r0, c0);
    for (int c = 0; c < 4; ++c) {
        for (int q = t; q < 1024; q += 256)
            *(float4*)(Wt + q * 4) = *(const float4*)(W3 + (size_t)c * 32 * 128 + q * 4);
        __syncthreads();
        gemm_chunk<32>(h2 + c * 32, 128, Wt, r0, c0, acc);
        __syncthreads();
    }
    float vals[4][4];
    ln_block(acc, b3, g, beta, c0, vals);
    int half = (c0 < 64);
    int cc = half ? c0 : (c0 - 64);
#pragma unroll
    for (int i = 0; i < 4; ++i) {
        int eid = e0 + r0 + i;
        if (eid < E_) {
            float4 eo = *(const float4*)(e + (size_t)eid * 128 + c0);
            float4 res = {eo.x + vals[i][0], eo.y + vals[i][1],
                          eo.z + vals[i][2], eo.w + vals[i][3]};
            *(float4*)(e + (size_t)eid * 128 + c0) = res;
            int dst = half ? sh_r[r0 + i] : sh_s[r0 + i];
            float* ap = agg + (size_t)dst * 64 + cc;
            atomicAdd(ap + 0, vals[i][0]);
            atomicAdd(ap + 1, vals[i][1]);
            atomicAdd(ap + 2, vals[i][2]);
            atomicAdd(ap + 3, vals[i][3]);
        }
    }
}

// ---------------- Node block: concat(x, agg) -> MLP(192,...) -> LN -> x += new
__global__ __launch_bounds__(256) void node_block_kernel(
    float* __restrict__ x, const float* __restrict__ agg,
    const float* __restrict__ W1, const float* __restrict__ b1,
    const float* __restrict__ W2, const float* __restrict__ b2,
    const float* __restrict__ W3, const float* __restrict__ b3,
    const float* __restrict__ g, const float* __restrict__ beta, int N_) {
    __shared__ __align__(16) float Ast[32 * 32];
    __shared__ __align__(16) float Wt[32 * 128];
    __shared__ __align__(16) float h1[32 * 128];
    __shared__ __align__(16) float h2[32 * 128];
    int t = threadIdx.x;
    int tx = t & 31, ty = t >> 5;
    int r0 = ty * 4, c0 = tx * 4;
    int n0 = blockIdx.x * 32;
    float acc[4][4] = {};
    // MLP1: K=192 in 6 chunks of 32 (0..3 x, 4..5 agg)
    for (int c = 0; c < 6; ++c) {
        {
            int row = t >> 3, fc = t & 7;
            int nid = min(n0 + row, N_ - 1);
            const float* src;
            if (c < 4) src = x + (size_t)nid * 128 + c * 32;
            else       src = agg + (size_t)nid * 64 + (c - 4) * 32;
            *(float4*)(Ast + row * 32 + fc * 4) = *(const float4*)(src + fc * 4);
        }
        for (int q = t; q < 1024; q += 256)
            *(float4*)(Wt + q * 4) = *(const float4*)(W1 + (size_t)c * 32 * 128 + q * 4);
        __syncthreads();
        gemm_chunk<32>(Ast, 32, Wt, r0, c0, acc);
        __syncthreads();
    }
    bias_gelu_store(acc, b1, h1, r0, c0);
    for (int c = 0; c < 4; ++c) {
        for (int q = t; q < 1024; q += 256)
            *(float4*)(Wt + q * 4) = *(const float4*)(W2 + (size_t)c * 32 * 128 + q * 4);
        __syncthreads();
        gemm_chunk<32>(h1 + c * 32, 128, Wt, r0, c0, acc);
        __syncthreads();
    }
    bias_gelu_store(acc, b2, h2, r0, c0);
    for (int c = 0; c < 4; ++c) {
        for (int q = t; q < 1024; q += 256)
            *(float4*)(Wt + q * 4) = *(const float4*)(W3 + (size_t)c * 32 * 128 + q * 4);
        __syncthreads();
        gemm_chunk<32>(h2 + c * 32, 128, Wt, r0, c0, acc);
        __syncthreads();
    }
    float vals[4][4];
    ln_block(acc, b3, g, beta, c0, vals);
#pragma unroll
    for (int i = 0; i < 4; ++i) {
        int nid = n0 + r0 + i;
        if (nid < N_) {
            float4 xo = *(const float4*)(x + (size_t)nid * 128 + c0);
            float4 res = {xo.x + vals[i][0], xo.y + vals[i][1],
                          xo.z + vals[i][2], xo.w + vals[i][3]};
            *(float4*)(x + (size_t)nid * 128 + c0) = res;
        }
    }
}

// ---------------- Decoder: MLP(128,128,128,3), no LN
__global__ __launch_bounds__(256) void dec_kernel(
    const float* __restrict__ xl,
    const float* __restrict__ W1, const float* __restrict__ b1,
    const float* __restrict__ W2, const float* __restrict__ b2,
    const float* __restrict__ W3, const float* __restrict__ b3,
    float* __restrict__ out, int N_) {
    __shared__ __align__(16) float Ast[32 * 32];
    __shared__ __align__(16) float Wt[32 * 128];
    __shared__ __align__(16) float h1[32 * 128];
    __shared__ __align__(16) float h2[32 * 128];
    int t = threadIdx.x;
    int tx = t & 31, ty = t >> 5;
    int r0 = ty * 4, c0 = tx * 4;
    int n0 = blockIdx.x * 32;
    float acc[4][4] = {};
    for (int c = 0; c < 4; ++c) {
        {
            int row = t >> 3, fc = t & 7;
            int nid = min(n0 + row, N_ - 1);
            const float* src = xl + (size_t)nid * 128 + c * 32;
            *(float4*)(Ast + row * 32 + fc * 4) = *(const float4*)(src + fc * 4);
        }
        for (int q = t; q < 1024; q += 256)
            *(float4*)(Wt + q * 4) = *(const float4*)(W1 + (size_t)c * 32 * 128 + q * 4);
        __syncthreads();
        gemm_chunk<32>(Ast, 32, Wt, r0, c0, acc);
        __syncthreads();
    }
    bias_gelu_store(acc, b1, h1, r0, c0);
    for (int c = 0; c < 4; ++c) {
        for (int q = t; q < 1024; q += 256)
            *(float4*)(Wt + q * 4) = *(const float4*)(W2 + (size_t)c * 32 * 128 + q * 4);
        __syncthreads();
        gemm_chunk<32>(h1 + c * 32, 128, Wt, r0, c0, acc);
        __syncthreads();
    }
    bias_gelu_store(acc, b2, h2, r0, c0);
    __syncthreads();
    // final 128 -> 3
    if (t < 96) {
        int r = t / 3, j = t - 3 * (t / 3);
        int nid = n0 + r;
        if (nid < N_) {
            float s = b3[j];
            for (int k = 0; k < 128; ++k) s = fmaf(h2[r * 128 + k], W3[k * 3 + j], s);
            out[(size_t)nid * 3 + j] = s;
        }
    }
}

static inline int cdiv(int a, int b) { return (a + b - 1) / b; }

extern "C" void kernel_launch(void* const* d_in, const int* in_sizes, int n_in,
                              void* d_out, int out_size, void* d_ws, size_t ws_size,
                              hipStream_t stream) {
    const float* x0 = (const float*)d_in[0];
    const float* ea0 = (const float*)d_in[1];
    const float* enW1 = (const float*)d_in[2];
    const float* enb1 = (const float*)d_in[3];
    const float* enW2 = (const float*)d_in[4];
    const float* enb2 = (const float*)d_in[5];
    const float* enW3 = (const float*)d_in[6];
    const float* enb3 = (const float*)d_in[7];
    const float* eng = (const float*)d_in[8];
    const float* enbt = (const float*)d_in[9];
    const float* eeW1 = (const float*)d_in[10];
    const float* eeb1 = (const float*)d_in[11];
    const float* eeW2 = (const float*)d_in[12];
    const float* eeb2 = (const float*)d_in[13];
    const float* eeW3 = (const float*)d_in[14];
    const float* eeb3 = (const float*)d_in[15];
    const float* eeg = (const float*)d_in[16];
    const float* eebt = (const float*)d_in[17];
    const float* beW1 = (const float*)d_in[18];
    const float* beb1 = (const float*)d_in[19];
    const float* beW2 = (const float*)d_in[20];
    const float* beb2 = (const float*)d_in[21];
    const float* beW3 = (const float*)d_in[22];
    const float* beb3 = (const float*)d_in[23];
    const float* beg = (const float*)d_in[24];
    const float* bebt = (const float*)d_in[25];
    const float* bnW1 = (const float*)d_in[26];
    const float* bnb1 = (const float*)d_in[27];
    const float* bnW2 = (const float*)d_in[28];
    const float* bnb2 = (const float*)d_in[29];
    const float* bnW3 = (const float*)d_in[30];
    const float* bnb3 = (const float*)d_in[31];
    const float* bng = (const float*)d_in[32];
    const float* bnbt = (const float*)d_in[33];
    const float* dW1 = (const float*)d_in[34];
    const float* db1 = (const float*)d_in[35];
    const float* dW2 = (const float*)d_in[36];
    const float* db2 = (const float*)d_in[37];
    const float* dW3 = (const float*)d_in[38];
    const float* db3 = (const float*)d_in[39];
    const int* ei = (const int*)d_in[40];
    const int* senders = ei;
    const int* receivers = ei + EE;

    float* ws = (float*)d_ws;
    float* xl = ws;                          // N*128
    float* el = xl + (size_t)NN * 128;       // E*128
    float* agg = el + (size_t)EE * 128;      // N*64

    dim3 blk(256);
    enc_kernel<<<cdiv(NN, 32), blk, 0, stream>>>(x0, xl, enW1, enb1, enW2, enb2, enW3,
                                                 enb3, eng, enbt, NN);
    enc_kernel<<<cdiv(EE, 32), blk, 0, stream>>>(ea0, el, eeW1, eeb1, eeW2, eeb2, eeW3,
                                                 eeb3, eeg, eebt, EE);
    for (int l = 0; l < LL; ++l) {
        hipMemsetAsync(agg, 0, (size_t)NN * 64 * sizeof(float), stream);
        edge_block_kernel<<<cdiv(EE, 32), blk, 0, stream>>>(
            xl, el, senders, receivers,
            beW1 + (size_t)l * 384 * 128, beb1 + (size_t)l * 128,
            beW2 + (size_t)l * 128 * 128, beb2 + (size_t)l * 128,
            beW3 + (size_t)l * 128 * 128, beb3 + (size_t)l * 128,
            beg + (size_t)l * 128, bebt + (size_t)l * 128, agg, EE);
        node_block_kernel<<<cdiv(NN, 32), blk, 0, stream>>>(
            xl, agg,
            bnW1 + (size_t)l * 192 * 128, bnb1 + (size_t)l * 128,
            bnW2 + (size_t)l * 128 * 128, bnb2 + (size_t)l * 128,
            bnW3 + (size_t)l * 128 * 128, bnb3 + (size_t)l * 128,
            bng + (size_t)l * 128, bnbt + (size_t)l * 128, NN);
    }
    dec_kernel<<<cdiv(NN, 32), blk, 0, stream>>>(xl, dW1, db1, dW2, db2, dW3, db3,
                                                 (float*)d_out, NN);
}

// Round 2
// 5994.557 us; speedup vs baseline: 1.5992x; 1.5992x over previous
//
#include <hip/hip_runtime.h>
#include <math.h>

// Problem constants (match reference setup_inputs)
#define NN 50000
#define EE 150000
#define LL 15

typedef __attribute__((ext_vector_type(8))) short short8;
typedef __attribute__((ext_vector_type(4))) float f32x4;

static __device__ __forceinline__ float gelu_f(float x) {
    // exact (erf) GELU, matches jax.nn.gelu(approximate=False)
    return 0.5f * x * (1.0f + erff(x * 0.70710678118654752440f));
}

static __device__ __forceinline__ unsigned short bf16_of(float f) {
    union { float f; unsigned u; } v;
    v.f = f;
    unsigned r = (v.u + 0x7fffu + ((v.u >> 16) & 1u)) >> 16;  // RNE
    return (unsigned short)r;
}

// ---------------- weight transpose+convert: in [C][K][N] fp32 -> out [C][N][K] bf16
__global__ __launch_bounds__(256) void wt_t_kernel(const float* __restrict__ in,
                                                   unsigned short* __restrict__ out,
                                                   int K, int N, int total) {
    int i = blockIdx.x * 256 + threadIdx.x;
    if (i >= total) return;
    int n = i % N;
    int t = i / N;
    int k = t % K;
    int c = t / K;
    out[((size_t)c * N + n) * K + k] = bf16_of(in[i]);
}

// ---------------- fp32 -> bf16 elementwise
__global__ __launch_bounds__(256) void f2b_kernel(const float* __restrict__ in,
                                                  unsigned short* __restrict__ out, int total4) {
    int i = blockIdx.x * 256 + threadIdx.x;
    if (i >= total4) return;
    float4 v = *(const float4*)(in + (size_t)i * 4);
    unsigned short o[4] = {bf16_of(v.x), bf16_of(v.y), bf16_of(v.z), bf16_of(v.w)};
    *(uint2*)(out + (size_t)i * 4) = *(uint2*)o;
}

// ================= MFMA edge block =================
// 64 edges/block, 4 waves; wave w owns rows [w*16, w*16+16), all 128 cols (8 n-tiles).
// A-frag: lane holds A[m=lane&15][k=q*8..q*8+7], q=lane>>4.  B same with n=lane&15 (W stored [n][k]).
// D: col=lane&15, row=q*4+reg.
__global__ __launch_bounds__(256) void edge_mfma_kernel(
    const unsigned short* __restrict__ xb, float* __restrict__ el,
    unsigned short* __restrict__ eb,
    const int* __restrict__ senders, const int* __restrict__ receivers,
    const unsigned short* __restrict__ W1t, const float* __restrict__ b1,
    const unsigned short* __restrict__ W2t, const float* __restrict__ b2,
    const unsigned short* __restrict__ W3t, const float* __restrict__ b3,
    const float* __restrict__ g, const float* __restrict__ beta,
    float* __restrict__ agg) {
    __shared__ __align__(16) unsigned short h[4][16][136];  // per-wave private slab, pad 136 (bank rotate 4)
    int t = threadIdx.x;
    int w = t >> 6;
    int l = t & 63;
    int m = l & 15;
    int q = l >> 4;
    int rbase = blockIdx.x * 64 + w * 16;

    int arow = rbase + m;
    if (arow >= EE) arow = EE - 1;
    int as = senders[arow], ar = receivers[arow];

    f32x4 acc[8];
#pragma unroll
    for (int nt = 0; nt < 8; ++nt) acc[nt] = (f32x4)0.f;

    // ---- MLP1: K=384 (12 chunks): 0..3 x[sender], 4..7 x[receiver], 8..11 e
#pragma unroll
    for (int c = 0; c < 12; ++c) {
        const unsigned short* ap;
        if (c < 4)      ap = xb + (size_t)as * 128 + c * 32 + q * 8;
        else if (c < 8) ap = xb + (size_t)ar * 128 + (c - 4) * 32 + q * 8;
        else            ap = eb + (size_t)arow * 128 + (c - 8) * 32 + q * 8;
        short8 af = *(const short8*)ap;
#pragma unroll
        for (int nt = 0; nt < 8; ++nt) {
            short8 bf = *(const short8*)(W1t + ((size_t)(nt * 16 + m)) * 384 + c * 32 + q * 8);
            acc[nt] = __builtin_amdgcn_mfma_f32_16x16x32_bf16(af, bf, acc[nt], 0, 0, 0);
        }
    }
    // bias+gelu -> h1 (wave-private slab; in-wave LDS hazards ordered by lgkmcnt)
#pragma unroll
    for (int nt = 0; nt < 8; ++nt) {
        float bv = b1[nt * 16 + m];
#pragma unroll
        for (int r = 0; r < 4; ++r)
            h[w][q * 4 + r][nt * 16 + m] = bf16_of(gelu_f(acc[nt][r] + bv));
        acc[nt] = (f32x4)0.f;
    }
    // ---- MLP2: K=128
#pragma unroll
    for (int c = 0; c < 4; ++c) {
        short8 af = *(const short8*)&h[w][m][c * 32 + q * 8];
#pragma unroll
        for (int nt = 0; nt < 8; ++nt) {
            short8 bf = *(const short8*)(W2t + ((size_t)(nt * 16 + m)) * 128 + c * 32 + q * 8);
            acc[nt] = __builtin_amdgcn_mfma_f32_16x16x32_bf16(af, bf, acc[nt], 0, 0, 0);
        }
    }
#pragma unroll
    for (int nt = 0; nt < 8; ++nt) {
        float bv = b2[nt * 16 + m];
#pragma unroll
        for (int r = 0; r < 4; ++r)
            h[w][q * 4 + r][nt * 16 + m] = bf16_of(gelu_f(acc[nt][r] + bv));
        acc[nt] = (f32x4)0.f;
    }
    // ---- MLP3: K=128
#pragma unroll
    for (int c = 0; c < 4; ++c) {
        short8 af = *(const short8*)&h[w][m][c * 32 + q * 8];
#pragma unroll
        for (int nt = 0; nt < 8; ++nt) {
            short8 bf = *(const short8*)(W3t + ((size_t)(nt * 16 + m)) * 128 + c * 32 + q * 8);
            acc[nt] = __builtin_amdgcn_mfma_f32_16x16x32_bf16(af, bf, acc[nt], 0, 0, 0);
        }
    }
    // ---- epilogue: bias, LN over 128 cols, residual, bf16 mirror, scatter-add
    float s[4] = {0.f, 0.f, 0.f, 0.f}, ss[4] = {0.f, 0.f, 0.f, 0.f};
    float vals[8][4];
#pragma unroll
    for (int nt = 0; nt < 8; ++nt) {
        float bv = b3[nt * 16 + m];
#pragma unroll
        for (int r = 0; r < 4; ++r) {
            float v = acc[nt][r] + bv;
            vals[nt][r] = v;
            s[r] += v;
            ss[r] += v * v;
        }
    }
#pragma unroll
    for (int r = 0; r < 4; ++r) {
#pragma unroll
        for (int msk = 1; msk < 16; msk <<= 1) {
            s[r] += __shfl_xor(s[r], msk, 64);
            ss[r] += __shfl_xor(ss[r], msk, 64);
        }
    }
#pragma unroll
    for (int r = 0; r < 4; ++r) {
        int row = rbase + q * 4 + r;
        if (row < EE) {
            float mean = s[r] * (1.0f / 128.0f);
            float var = ss[r] * (1.0f / 128.0f) - mean * mean;
            float rstd = rsqrtf(var + 1e-5f);
            int snd = senders[row], rcv = receivers[row];
#pragma unroll
            for (int nt = 0; nt < 8; ++nt) {
                int col = nt * 16 + m;
                float v = (vals[nt][r] - mean) * rstd * g[col] + beta[col];
                size_t off = (size_t)row * 128 + col;
                float res = el[off] + v;
                el[off] = res;
                eb[off] = bf16_of(res);
                if (col < 64) atomicAdd(agg + (size_t)rcv * 64 + col, v);
                else          atomicAdd(agg + (size_t)snd * 64 + (col - 64), v);
            }
        }
    }
}

// ================= MFMA node block =================
__global__ __launch_bounds__(256) void node_mfma_kernel(
    float* __restrict__ xl, unsigned short* __restrict__ xb,
    const float* __restrict__ agg,
    const unsigned short* __restrict__ W1t, const float* __restrict__ b1,
    const unsigned short* __restrict__ W2t, const float* __restrict__ b2,
    const unsigned short* __restrict__ W3t, const float* __restrict__ b3,
    const float* __restrict__ g, const float* __restrict__ beta) {
    __shared__ __align__(16) unsigned short h[4][16][136];
    int t = threadIdx.x;
    int w = t >> 6;
    int l = t & 63;
    int m = l & 15;
    int q = l >> 4;
    int rbase = blockIdx.x * 64 + w * 16;
    int arow = rbase + m;
    if (arow >= NN) arow = NN - 1;

    f32x4 acc[8];
#pragma unroll
    for (int nt = 0; nt < 8; ++nt) acc[nt] = (f32x4)0.f;

    // ---- MLP1: K=192 (6 chunks): 0..3 x, 4..5 agg (fp32 -> bf16 on the fly)
#pragma unroll
    for (int c = 0; c < 6; ++c) {
        short8 af;
        if (c < 4) {
            af = *(const short8*)(xb + (size_t)arow * 128 + c * 32 + q * 8);
        } else {
            const float* fp = agg + (size_t)arow * 64 + (c - 4) * 32 + q * 8;
            float4 f0 = *(const float4*)fp;
            float4 f1 = *(const float4*)(fp + 4);
            af[0] = (short)bf16_of(f0.x); af[1] = (short)bf16_of(f0.y);
            af[2] = (short)bf16_of(f0.z); af[3] = (short)bf16_of(f0.w);
            af[4] = (short)bf16_of(f1.x); af[5] = (short)bf16_of(f1.y);
            af[6] = (short)bf16_of(f1.z); af[7] = (short)bf16_of(f1.w);
        }
#pragma unroll
        for (int nt = 0; nt < 8; ++nt) {
            short8 bf = *(const short8*)(W1t + ((size_t)(nt * 16 + m)) * 192 + c * 32 + q * 8);
            acc[nt] = __builtin_amdgcn_mfma_f32_16x16x32_bf16(af, bf, acc[nt], 0, 0, 0);
        }
    }
#pragma unroll
    for (int nt = 0; nt < 8; ++nt) {
        float bv = b1[nt * 16 + m];
#pragma unroll
        for (int r = 0; r < 4; ++r)
            h[w][q * 4 + r][nt * 16 + m] = bf16_of(gelu_f(acc[nt][r] + bv));
        acc[nt] = (f32x4)0.f;
    }
#pragma unroll
    for (int c = 0; c < 4; ++c) {
        short8 af = *(const short8*)&h[w][m][c * 32 + q * 8];
#pragma unroll
        for (int nt = 0; nt < 8; ++nt) {
            short8 bf = *(const short8*)(W2t + ((size_t)(nt * 16 + m)) * 128 + c * 32 + q * 8);
            acc[nt] = __builtin_amdgcn_mfma_f32_16x16x32_bf16(af, bf, acc[nt], 0, 0, 0);
        }
    }
#pragma unroll
    for (int nt = 0; nt < 8; ++nt) {
        float bv = b2[nt * 16 + m];
#pragma unroll
        for (int r = 0; r < 4; ++r)
            h[w][q * 4 + r][nt * 16 + m] = bf16_of(gelu_f(acc[nt][r] + bv));
        acc[nt] = (f32x4)0.f;
    }
#pragma unroll
    for (int c = 0; c < 4; ++c) {
        short8 af = *(const short8*)&h[w][m][c * 32 + q * 8];
#pragma unroll
        for (int nt = 0; nt < 8; ++nt) {
            short8 bf = *(const short8*)(W3t + ((size_t)(nt * 16 + m)) * 128 + c * 32 + q * 8);
            acc[nt] = __builtin_amdgcn_mfma_f32_16x16x32_bf16(af, bf, acc[nt], 0, 0, 0);
        }
    }
    // epilogue
    float s[4] = {0.f, 0.f, 0.f, 0.f}, ss[4] = {0.f, 0.f, 0.f, 0.f};
    float vals[8][4];
#pragma unroll
    for (int nt = 0; nt < 8; ++nt) {
        float bv = b3[nt * 16 + m];
#pragma unroll
        for (int r = 0; r < 4; ++r) {
            float v = acc[nt][r] + bv;
            vals[nt][r] = v;
            s[r] += v;
            ss[r] += v * v;
        }
    }
#pragma unroll
    for (int r = 0; r < 4; ++r) {
#pragma unroll
        for (int msk = 1; msk < 16; msk <<= 1) {
            s[r] += __shfl_xor(s[r], msk, 64);
            ss[r] += __shfl_xor(ss[r], msk, 64);
        }
    }
#pragma unroll
    for (int r = 0; r < 4; ++r) {
        int row = rbase + q * 4 + r;
        if (row < NN) {
            float mean = s[r] * (1.0f / 128.0f);
            float var = ss[r] * (1.0f / 128.0f) - mean * mean;
            float rstd = rsqrtf(var + 1e-5f);
#pragma unroll
            for (int nt = 0; nt < 8; ++nt) {
                int col = nt * 16 + m;
                float v = (vals[nt][r] - mean) * rstd * g[col] + beta[col];
                size_t off = (size_t)row * 128 + col;
                float res = xl[off] + v;
                xl[off] = res;
                xb[off] = bf16_of(res);
            }
        }
    }
}

// ================= fp32 encoder (unchanged from R1) =================
template <int KC>
static __device__ __forceinline__ void gemm_chunk(const float* A, int lda, const float* W,
                                                  int r0, int c0, float acc[4][4]) {
#pragma unroll
    for (int kk = 0; kk < KC; kk += 4) {
        float4 a[4];
        float4 w[4];
#pragma unroll
        for (int i = 0; i < 4; ++i) a[i] = *(const float4*)(A + (r0 + i) * lda + kk);
#pragma unroll
        for (int mm = 0; mm < 4; ++mm) w[mm] = *(const float4*)(W + (kk + mm) * 128 + c0);
#pragma unroll
        for (int i = 0; i < 4; ++i) {
            float am[4] = {a[i].x, a[i].y, a[i].z, a[i].w};
#pragma unroll
            for (int mm = 0; mm < 4; ++mm) {
                acc[i][0] = fmaf(am[mm], w[mm].x, acc[i][0]);
                acc[i][1] = fmaf(am[mm], w[mm].y, acc[i][1]);
                acc[i][2] = fmaf(am[mm], w[mm].z, acc[i][2]);
                acc[i][3] = fmaf(am[mm], w[mm].w, acc[i][3]);
            }
        }
    }
}

static __device__ __forceinline__ void bias_gelu_store(float acc[4][4], const float* __restrict__ b,
                                                       float* h, int r0, int c0) {
    float4 bb = *(const float4*)(b + c0);
    float bv[4] = {bb.x, bb.y, bb.z, bb.w};
#pragma unroll
    for (int i = 0; i < 4; ++i) {
        float4 o;
        o.x = gelu_f(acc[i][0] + bv[0]);
        o.y = gelu_f(acc[i][1] + bv[1]);
        o.z = gelu_f(acc[i][2] + bv[2]);
        o.w = gelu_f(acc[i][3] + bv[3]);
        *(float4*)(h + (r0 + i) * 128 + c0) = o;
#pragma unroll
        for (int j = 0; j < 4; ++j) acc[i][j] = 0.f;
    }
}

static __device__ __forceinline__ void ln_block(float acc[4][4], const float* __restrict__ b,
                                                const float* __restrict__ g,
                                                const float* __restrict__ beta, int c0,
                                                float vals[4][4]) {
    float4 bb = *(const float4*)(b + c0);
    float bv[4] = {bb.x, bb.y, bb.z, bb.w};
    float4 gg = *(const float4*)(g + c0);
    float gv[4] = {gg.x, gg.y, gg.z, gg.w};
    float4 bt = *(const float4*)(beta + c0);
    float btv[4] = {bt.x, bt.y, bt.z, bt.w};
#pragma unroll
    for (int i = 0; i < 4; ++i) {
        float v[4];
#pragma unroll
        for (int j = 0; j < 4; ++j) v[j] = acc[i][j] + bv[j];
        float sm = v[0] + v[1] + v[2] + v[3];
        float sq = v[0] * v[0] + v[1] * v[1] + v[2] * v[2] + v[3] * v[3];
#pragma unroll
        for (int mk = 1; mk < 32; mk <<= 1) {
            sm += __shfl_xor(sm, mk, 64);
            sq += __shfl_xor(sq, mk, 64);
        }
        float mean = sm * (1.0f / 128.0f);
        float var = sq * (1.0f / 128.0f) - mean * mean;
        float rstd = rsqrtf(var + 1e-5f);
#pragma unroll
        for (int j = 0; j < 4; ++j) vals[i][j] = (v[j] - mean) * rstd * gv[j] + btv[j];
    }
}

__global__ __launch_bounds__(256) void enc_kernel(
    const float* __restrict__ in, float* __restrict__ out,
    const float* __restrict__ W1, const float* __restrict__ b1,
    const float* __restrict__ W2, const float* __restrict__ b2,
    const float* __restrict__ W3, const float* __restrict__ b3,
    const float* __restrict__ g, const float* __restrict__ beta, int nrows) {
    __shared__ __align__(16) float Ast[32 * 16];
    __shared__ __align__(16) float Wt[32 * 128];
    __shared__ __align__(16) float h1[32 * 128];
    __shared__ __align__(16) float h2[32 * 128];
    int t = threadIdx.x;
    int tx = t & 31, ty = t >> 5;
    int r0 = ty * 4, c0 = tx * 4;
    int n0 = blockIdx.x * 32;

    if (t < 128) {
        int row = t >> 2, fc = t & 3;
        int rid = min(n0 + row, nrows - 1);
        *(float4*)(Ast + row * 16 + fc * 4) = *(const float4*)(in + (size_t)rid * 16 + fc * 4);
    }
    for (int qq = t; qq < 512; qq += 256)
        *(float4*)(Wt + qq * 4) = *(const float4*)(W1 + (size_t)qq * 4);
    __syncthreads();
    float acc[4][4] = {};
    gemm_chunk<16>(Ast, 16, Wt, r0, c0, acc);
    __syncthreads();
    bias_gelu_store(acc, b1, h1, r0, c0);
    for (int c = 0; c < 4; ++c) {
        for (int qq = t; qq < 1024; qq += 256)
            *(float4*)(Wt + qq * 4) = *(const float4*)(W2 + (size_t)c * 32 * 128 + qq * 4);
        __syncthreads();
        gemm_chunk<32>(h1 + c * 32, 128, Wt, r0, c0, acc);
        __syncthreads();
    }
    bias_gelu_store(acc, b2, h2, r0, c0);
    for (int c = 0; c < 4; ++c) {
        for (int qq = t; qq < 1024; qq += 256)
            *(float4*)(Wt + qq * 4) = *(const float4*)(W3 + (size_t)c * 32 * 128 + qq * 4);
        __syncthreads();
        gemm_chunk<32>(h2 + c * 32, 128, Wt, r0, c0, acc);
        __syncthreads();
    }
    float vals[4][4];
    ln_block(acc, b3, g, beta, c0, vals);
#pragma unroll
    for (int i = 0; i < 4; ++i) {
        int rid = n0 + r0 + i;
        if (rid < nrows) {
            float4 o = {vals[i][0], vals[i][1], vals[i][2], vals[i][3]};
            *(float4*)(out + (size_t)rid * 128 + c0) = o;
        }
    }
}

__global__ __launch_bounds__(256) void dec_kernel(
    const float* __restrict__ xl,
    const float* __restrict__ W1, const float* __restrict__ b1,
    const float* __restrict__ W2, const float* __restrict__ b2,
    const float* __restrict__ W3, const float* __restrict__ b3,
    float* __restrict__ out, int N_) {
    __shared__ __align__(16) float Ast[32 * 32];
    __shared__ __align__(16) float Wt[32 * 128];
    __shared__ __align__(16) float h1[32 * 128];
    __shared__ __align__(16) float h2[32 * 128];
    int t = threadIdx.x;
    int tx = t & 31, ty = t >> 5;
    int r0 = ty * 4, c0 = tx * 4;
    int n0 = blockIdx.x * 32;
    float acc[4][4] = {};
    for (int c = 0; c < 4; ++c) {
        {
            int row = t >> 3, fc = t & 7;
            int nid = min(n0 + row, N_ - 1);
            const float* src = xl + (size_t)nid * 128 + c * 32;
            *(float4*)(Ast + row * 32 + fc * 4) = *(const float4*)(src + fc * 4);
        }
        for (int qq = t; qq < 1024; qq += 256)
            *(float4*)(Wt + qq * 4) = *(const float4*)(W1 + (size_t)c * 32 * 128 + qq * 4);
        __syncthreads();
        gemm_chunk<32>(Ast, 32, Wt, r0, c0, acc);
        __syncthreads();
    }
    bias_gelu_store(acc, b1, h1, r0, c0);
    for (int c = 0; c < 4; ++c) {
        for (int qq = t; qq < 1024; qq += 256)
            *(float4*)(Wt + qq * 4) = *(const float4*)(W2 + (size_t)c * 32 * 128 + qq * 4);
        __syncthreads();
        gemm_chunk<32>(h1 + c * 32, 128, Wt, r0, c0, acc);
        __syncthreads();
    }
    bias_gelu_store(acc, b2, h2, r0, c0);
    __syncthreads();
    if (t < 96) {
        int r = t / 3, j = t - 3 * (t / 3);
        int nid = n0 + r;
        if (nid < N_) {
            float s = b3[j];
            for (int k = 0; k < 128; ++k) s = fmaf(h2[r * 128 + k], W3[k * 3 + j], s);
            out[(size_t)nid * 3 + j] = s;
        }
    }
}

static inline int cdiv(int a, int b) { return (a + b - 1) / b; }

extern "C" void kernel_launch(void* const* d_in, const int* in_sizes, int n_in,
                              void* d_out, int out_size, void* d_ws, size_t ws_size,
                              hipStream_t stream) {
    const float* x0 = (const float*)d_in[0];
    const float* ea0 = (const float*)d_in[1];
    const float* enW1 = (const float*)d_in[2];
    const float* enb1 = (const float*)d_in[3];
    const float* enW2 = (const float*)d_in[4];
    const float* enb2 = (const float*)d_in[5];
    const float* enW3 = (const float*)d_in[6];
    const float* enb3 = (const float*)d_in[7];
    const float* eng = (const float*)d_in[8];
    const float* enbt = (const float*)d_in[9];
    const float* eeW1 = (const float*)d_in[10];
    const float* eeb1 = (const float*)d_in[11];
    const float* eeW2 = (const float*)d_in[12];
    const float* eeb2 = (const float*)d_in[13];
    const float* eeW3 = (const float*)d_in[14];
    const float* eeb3 = (const float*)d_in[15];
    const float* eeg = (const float*)d_in[16];
    const float* eebt = (const float*)d_in[17];
    const float* beW1 = (const float*)d_in[18];
    const float* beb1 = (const float*)d_in[19];
    const float* beW2 = (const float*)d_in[20];
    const float* beb2 = (const float*)d_in[21];
    const float* beW3 = (const float*)d_in[22];
    const float* beb3 = (const float*)d_in[23];
    const float* beg = (const float*)d_in[24];
    const float* bebt = (const float*)d_in[25];
    const float* bnW1 = (const float*)d_in[26];
    const float* bnb1 = (const float*)d_in[27];
    const float* bnW2 = (const float*)d_in[28];
    const float* bnb2 = (const float*)d_in[29];
    const float* bnW3 = (const float*)d_in[30];
    const float* bnb3 = (const float*)d_in[31];
    const float* bng = (const float*)d_in[32];
    const float* bnbt = (const float*)d_in[33];
    const float* dW1 = (const float*)d_in[34];
    const float* db1 = (const float*)d_in[35];
    const float* dW2 = (const float*)d_in[36];
    const float* db2 = (const float*)d_in[37];
    const float* dW3 = (const float*)d_in[38];
    const float* db3 = (const float*)d_in[39];
    const int* ei = (const int*)d_in[40];
    const int* senders = ei;
    const int* receivers = ei + EE;

    // ---- workspace layout
    char* p = (char*)d_ws;
    float* xl = (float*)p;              p += (size_t)NN * 128 * 4;
    float* el = (float*)p;              p += (size_t)EE * 128 * 4;
    float* agg = (float*)p;             p += (size_t)NN * 64 * 4;
    unsigned short* xb = (unsigned short*)p;  p += (size_t)NN * 128 * 2;
    unsigned short* eb = (unsigned short*)p;  p += (size_t)EE * 128 * 2;
    unsigned short* ew1t = (unsigned short*)p; p += (size_t)LL * 128 * 384 * 2;
    unsigned short* ew2t = (unsigned short*)p; p += (size_t)LL * 128 * 128 * 2;
    unsigned short* ew3t = (unsigned short*)p; p += (size_t)LL * 128 * 128 * 2;
    unsigned short* nw1t = (unsigned short*)p; p += (size_t)LL * 128 * 192 * 2;
    unsigned short* nw2t = (unsigned short*)p; p += (size_t)LL * 128 * 128 * 2;
    unsigned short* nw3t = (unsigned short*)p; p += (size_t)LL * 128 * 128 * 2;

    dim3 blk(256);
    // ---- weight convert+transpose (per launch; cheap)
    {
        int tot;
        tot = LL * 384 * 128;
        wt_t_kernel<<<cdiv(tot, 256), blk, 0, stream>>>(beW1, ew1t, 384, 128, tot);
        tot = LL * 128 * 128;
        wt_t_kernel<<<cdiv(tot, 256), blk, 0, stream>>>(beW2, ew2t, 128, 128, tot);
        wt_t_kernel<<<cdiv(tot, 256), blk, 0, stream>>>(beW3, ew3t, 128, 128, tot);
        wt_t_kernel<<<cdiv(tot, 256), blk, 0, stream>>>(bnW2, nw2t, 128, 128, tot);
        wt_t_kernel<<<cdiv(tot, 256), blk, 0, stream>>>(bnW3, nw3t, 128, 128, tot);
        tot = LL * 192 * 128;
        wt_t_kernel<<<cdiv(tot, 256), blk, 0, stream>>>(bnW1, nw1t, 192, 128, tot);
    }
    // ---- encoders (fp32) + bf16 mirrors
    enc_kernel<<<cdiv(NN, 32), blk, 0, stream>>>(x0, xl, enW1, enb1, enW2, enb2, enW3,
                                                 enb3, eng, enbt, NN);
    enc_kernel<<<cdiv(EE, 32), blk, 0, stream>>>(ea0, el, eeW1, eeb1, eeW2, eeb2, eeW3,
                                                 eeb3, eeg, eebt, EE);
    f2b_kernel<<<cdiv(NN * 32, 256), blk, 0, stream>>>(xl, xb, NN * 32);
    f2b_kernel<<<cdiv(EE * 32, 256), blk, 0, stream>>>(el, eb, EE * 32);

    // ---- 15 message-passing layers
    for (int l = 0; l < LL; ++l) {
        hipMemsetAsync(agg, 0, (size_t)NN * 64 * sizeof(float), stream);
        edge_mfma_kernel<<<cdiv(EE, 64), blk, 0, stream>>>(
            xb, el, eb, senders, receivers,
            ew1t + (size_t)l * 128 * 384, beb1 + (size_t)l * 128,
            ew2t + (size_t)l * 128 * 128, beb2 + (size_t)l * 128,
            ew3t + (size_t)l * 128 * 128, beb3 + (size_t)l * 128,
            beg + (size_t)l * 128, bebt + (size_t)l * 128, agg);
        node_mfma_kernel<<<cdiv(NN, 64), blk, 0, stream>>>(
            xl, xb, agg,
            nw1t + (size_t)l * 128 * 192, bnb1 + (size_t)l * 128,
            nw2t + (size_t)l * 128 * 128, bnb2 + (size_t)l * 128,
            nw3t + (size_t)l * 128 * 128, bnb3 + (size_t)l * 128,
            bng + (size_t)l * 128, bnbt + (size_t)l * 128);
    }
    // ---- decoder (fp32)
    dec_kernel<<<cdiv(NN, 32), blk, 0, stream>>>(xl, dW1, db1, dW2, db2, dW3, db3,
                                                 (float*)d_out, NN);
}

// Round 3
// 5028.529 us; speedup vs baseline: 1.9065x; 1.1921x over previous
//
#include <hip/hip_runtime.h>
#include <math.h>

// Problem constants (match reference setup_inputs)
#define NN 50000
#define EE 150000
#define LL 15

typedef __attribute__((ext_vector_type(8))) short short8;
typedef __attribute__((ext_vector_type(4))) float f32x4;

static __device__ __forceinline__ float gelu_f(float x) {
    return 0.5f * x * (1.0f + erff(x * 0.70710678118654752440f));
}

static __device__ __forceinline__ unsigned short bf16_of(float f) {
    union { float f; unsigned u; } v;
    v.f = f;
    unsigned r = (v.u + 0x7fffu + ((v.u >> 16) & 1u)) >> 16;  // RNE
    return (unsigned short)r;
}

static __device__ __forceinline__ float f_of_bf16(unsigned short u) {
    union { unsigned u; float f; } v;
    v.u = ((unsigned)u) << 16;
    return v.f;
}

// ---------------- weight transpose+convert: in [C][K][N] fp32 -> out [C][N][K] bf16
__global__ __launch_bounds__(256) void wt_t_kernel(const float* __restrict__ in,
                                                   unsigned short* __restrict__ out,
                                                   int K, int N, int total) {
    int i = blockIdx.x * 256 + threadIdx.x;
    if (i >= total) return;
    int n = i % N;
    int t = i / N;
    int k = t % K;
    int c = t / K;
    out[((size_t)c * N + n) * K + k] = bf16_of(in[i]);
}

// ---------------- fp32 -> bf16 elementwise (for xb mirror)
__global__ __launch_bounds__(256) void f2b_kernel(const float* __restrict__ in,
                                                  unsigned short* __restrict__ out, int total4) {
    int i = blockIdx.x * 256 + threadIdx.x;
    if (i >= total4) return;
    float4 v = *(const float4*)(in + (size_t)i * 4);
    unsigned short o[4] = {bf16_of(v.x), bf16_of(v.y), bf16_of(v.z), bf16_of(v.w)};
    *(uint2*)(out + (size_t)i * 4) = *(uint2*)o;
}

// ---------------- CSR build: histogram
__global__ __launch_bounds__(256) void hist_kernel(const int* __restrict__ senders,
                                                   const int* __restrict__ receivers,
                                                   int* __restrict__ cntR, int* __restrict__ cntS) {
    int i = blockIdx.x * 256 + threadIdx.x;
    if (i >= EE) return;
    atomicAdd(&cntR[receivers[i]], 1);
    atomicAdd(&cntS[senders[i]], 1);
}

// ---------------- CSR build: single-block scan over NN entries (R and S together)
__global__ __launch_bounds__(1024) void scan_kernel(const int* __restrict__ cntR,
                                                    const int* __restrict__ cntS,
                                                    int* __restrict__ offR, int* __restrict__ offS,
                                                    int* __restrict__ curR, int* __restrict__ curS) {
    __shared__ int pR[1024], pS[1024];
    int t = threadIdx.x;
    const int SPAN = 49;  // 1024*49 >= 50000
    int base = t * SPAN;
    int sumR = 0, sumS = 0;
    for (int i = 0; i < SPAN; ++i) {
        int idx = base + i;
        if (idx < NN) { sumR += cntR[idx]; sumS += cntS[idx]; }
    }
    pR[t] = sumR;
    pS[t] = sumS;
    __syncthreads();
    for (int off = 1; off < 1024; off <<= 1) {
        int vR = 0, vS = 0;
        if (t >= off) { vR = pR[t - off]; vS = pS[t - off]; }
        __syncthreads();
        pR[t] += vR;
        pS[t] += vS;
        __syncthreads();
    }
    int runR = pR[t] - sumR;
    int runS = pS[t] - sumS;
    for (int i = 0; i < SPAN; ++i) {
        int idx = base + i;
        if (idx < NN) {
            offR[idx] = runR; curR[idx] = runR; runR += cntR[idx];
            offS[idx] = runS; curS[idx] = runS; runS += cntS[idx];
        }
    }
    if (t == 1023) { offR[NN] = pR[1023]; offS[NN] = pS[1023]; }
}

// ---------------- CSR build: fill edge lists
__global__ __launch_bounds__(256) void fill_kernel(const int* __restrict__ senders,
                                                   const int* __restrict__ receivers,
                                                   int* __restrict__ curR, int* __restrict__ curS,
                                                   int* __restrict__ csrR, int* __restrict__ csrS) {
    int i = blockIdx.x * 256 + threadIdx.x;
    if (i >= EE) return;
    int pr = atomicAdd(&curR[receivers[i]], 1);
    csrR[pr] = i;
    int ps = atomicAdd(&curS[senders[i]], 1);
    csrS[ps] = i;
}

// ================= MFMA edge block =================
// 128 edges/block, 4 waves x 32 rows (2 m-tiles of 16); wave covers all 128 cols (8 n-tiles).
// A-frag: lane holds A[m=lane&15][k=q*8..+8], q=lane>>4; B same with n=lane&15 (W stored [n][k]).
// D: col=lane&15, row=q*4+reg.
__global__ __launch_bounds__(256) void edge_mfma_kernel(
    const unsigned short* __restrict__ xb, float* __restrict__ el,
    unsigned short* __restrict__ enew,
    const int* __restrict__ senders, const int* __restrict__ receivers,
    const unsigned short* __restrict__ W1t, const float* __restrict__ b1,
    const unsigned short* __restrict__ W2t, const float* __restrict__ b2,
    const unsigned short* __restrict__ W3t, const float* __restrict__ b3,
    const float* __restrict__ g, const float* __restrict__ beta) {
    __shared__ __align__(16) unsigned short h[4][32][136];  // per-wave slab, pad to 136
    int t = threadIdx.x;
    int w = t >> 6;
    int l = t & 63;
    int m = l & 15;
    int q = l >> 4;
    int rbase = blockIdx.x * 128 + w * 32;

    int arow[2], as[2], ar[2];
#pragma unroll
    for (int mt = 0; mt < 2; ++mt) {
        int rw = rbase + mt * 16 + m;
        if (rw >= EE) rw = EE - 1;
        arow[mt] = rw;
        as[mt] = senders[rw];
        ar[mt] = receivers[rw];
    }

    f32x4 acc0[8], acc1[8];
#pragma unroll
    for (int nt = 0; nt < 8; ++nt) { acc0[nt] = (f32x4)0.f; acc1[nt] = (f32x4)0.f; }

    // ---- MLP1: K=384 (12 chunks): 0..3 x[sender], 4..7 x[receiver], 8..11 e (fp32->bf16)
#pragma unroll
    for (int c = 0; c < 12; ++c) {
        short8 af[2];
#pragma unroll
        for (int mt = 0; mt < 2; ++mt) {
            if (c < 4) {
                af[mt] = *(const short8*)(xb + (size_t)as[mt] * 128 + c * 32 + q * 8);
            } else if (c < 8) {
                af[mt] = *(const short8*)(xb + (size_t)ar[mt] * 128 + (c - 4) * 32 + q * 8);
            } else {
                const float* fp = el + (size_t)arow[mt] * 128 + (c - 8) * 32 + q * 8;
                float4 f0 = *(const float4*)fp;
                float4 f1 = *(const float4*)(fp + 4);
                short8 a;
                a[0] = (short)bf16_of(f0.x); a[1] = (short)bf16_of(f0.y);
                a[2] = (short)bf16_of(f0.z); a[3] = (short)bf16_of(f0.w);
                a[4] = (short)bf16_of(f1.x); a[5] = (short)bf16_of(f1.y);
                a[6] = (short)bf16_of(f1.z); a[7] = (short)bf16_of(f1.w);
                af[mt] = a;
            }
        }
#pragma unroll
        for (int nt = 0; nt < 8; ++nt) {
            short8 bf = *(const short8*)(W1t + ((size_t)(nt * 16 + m)) * 384 + c * 32 + q * 8);
            acc0[nt] = __builtin_amdgcn_mfma_f32_16x16x32_bf16(af[0], bf, acc0[nt], 0, 0, 0);
            acc1[nt] = __builtin_amdgcn_mfma_f32_16x16x32_bf16(af[1], bf, acc1[nt], 0, 0, 0);
        }
    }
    // bias+gelu -> h (wave-private slab; same-wave LDS ordering via lgkmcnt)
#pragma unroll
    for (int nt = 0; nt < 8; ++nt) {
        float bv = b1[nt * 16 + m];
#pragma unroll
        for (int r = 0; r < 4; ++r) {
            h[w][q * 4 + r][nt * 16 + m] = bf16_of(gelu_f(acc0[nt][r] + bv));
            h[w][16 + q * 4 + r][nt * 16 + m] = bf16_of(gelu_f(acc1[nt][r] + bv));
        }
        acc0[nt] = (f32x4)0.f;
        acc1[nt] = (f32x4)0.f;
    }
    // ---- MLP2: K=128
#pragma unroll
    for (int c = 0; c < 4; ++c) {
        short8 af0 = *(const short8*)&h[w][m][c * 32 + q * 8];
        short8 af1 = *(const short8*)&h[w][16 + m][c * 32 + q * 8];
#pragma unroll
        for (int nt = 0; nt < 8; ++nt) {
            short8 bf = *(const short8*)(W2t + ((size_t)(nt * 16 + m)) * 128 + c * 32 + q * 8);
            acc0[nt] = __builtin_amdgcn_mfma_f32_16x16x32_bf16(af0, bf, acc0[nt], 0, 0, 0);
            acc1[nt] = __builtin_amdgcn_mfma_f32_16x16x32_bf16(af1, bf, acc1[nt], 0, 0, 0);
        }
    }
#pragma unroll
    for (int nt = 0; nt < 8; ++nt) {
        float bv = b2[nt * 16 + m];
#pragma unroll
        for (int r = 0; r < 4; ++r) {
            h[w][q * 4 + r][nt * 16 + m] = bf16_of(gelu_f(acc0[nt][r] + bv));
            h[w][16 + q * 4 + r][nt * 16 + m] = bf16_of(gelu_f(acc1[nt][r] + bv));
        }
        acc0[nt] = (f32x4)0.f;
        acc1[nt] = (f32x4)0.f;
    }
    // ---- MLP3: K=128
#pragma unroll
    for (int c = 0; c < 4; ++c) {
        short8 af0 = *(const short8*)&h[w][m][c * 32 + q * 8];
        short8 af1 = *(const short8*)&h[w][16 + m][c * 32 + q * 8];
#pragma unroll
        for (int nt = 0; nt < 8; ++nt) {
            short8 bf = *(const short8*)(W3t + ((size_t)(nt * 16 + m)) * 128 + c * 32 + q * 8);
            acc0[nt] = __builtin_amdgcn_mfma_f32_16x16x32_bf16(af0, bf, acc0[nt], 0, 0, 0);
            acc1[nt] = __builtin_amdgcn_mfma_f32_16x16x32_bf16(af1, bf, acc1[nt], 0, 0, 0);
        }
    }
    // ---- epilogue per m-tile: bias, LN over 128 cols, residual into el, e_new -> bf16
#pragma unroll
    for (int mt = 0; mt < 2; ++mt) {
        f32x4* acc = mt ? acc1 : acc0;
        float s[4] = {0.f, 0.f, 0.f, 0.f}, ss[4] = {0.f, 0.f, 0.f, 0.f};
#pragma unroll
        for (int nt = 0; nt < 8; ++nt) {
            float bv = b3[nt * 16 + m];
#pragma unroll
            for (int r = 0; r < 4; ++r) {
                float v = acc[nt][r] + bv;
                acc[nt][r] = v;
                s[r] += v;
                ss[r] += v * v;
            }
        }
#pragma unroll
        for (int r = 0; r < 4; ++r) {
#pragma unroll
            for (int msk = 1; msk < 16; msk <<= 1) {
                s[r] += __shfl_xor(s[r], msk, 64);
                ss[r] += __shfl_xor(ss[r], msk, 64);
            }
        }
#pragma unroll
        for (int r = 0; r < 4; ++r) {
            int row = rbase + mt * 16 + q * 4 + r;
            if (row < EE) {
                float mean = s[r] * (1.0f / 128.0f);
                float var = ss[r] * (1.0f / 128.0f) - mean * mean;
                float rstd = rsqrtf(var + 1e-5f);
#pragma unroll
                for (int nt = 0; nt < 8; ++nt) {
                    int col = nt * 16 + m;
                    float v = (acc[nt][r] - mean) * rstd * g[col] + beta[col];
                    size_t off = (size_t)row * 128 + col;
                    el[off] = el[off] + v;
                    enew[off] = bf16_of(v);
                }
            }
        }
    }
}

// ================= MFMA node block =================
// 128 nodes/block, 4 waves x 32 rows. Prologue: each lane gathers its own agg
// columns (q*8..+8 and 32+q*8..+8 for both m-tiles) from enew via CSR. No atomics.
__global__ __launch_bounds__(256) void node_mfma_kernel(
    float* __restrict__ xl, unsigned short* __restrict__ xb,
    const unsigned short* __restrict__ enew,
    const int* __restrict__ offR, const int* __restrict__ csrR,
    const int* __restrict__ offS, const int* __restrict__ csrS,
    const unsigned short* __restrict__ W1t, const float* __restrict__ b1,
    const unsigned short* __restrict__ W2t, const float* __restrict__ b2,
    const unsigned short* __restrict__ W3t, const float* __restrict__ b3,
    const float* __restrict__ g, const float* __restrict__ beta) {
    __shared__ __align__(16) unsigned short h[4][32][136];
    int t = threadIdx.x;
    int w = t >> 6;
    int l = t & 63;
    int m = l & 15;
    int q = l >> 4;
    int rbase = blockIdx.x * 128 + w * 32;

    // ---- aggregation prologue: aggv[mt][0..7] = agg cols q*8..+8, [8..15] = cols 32+q*8..+8
    float aggv[2][16];
#pragma unroll
    for (int mt = 0; mt < 2; ++mt)
#pragma unroll
        for (int j = 0; j < 16; ++j) aggv[mt][j] = 0.f;
#pragma unroll
    for (int mt = 0; mt < 2; ++mt) {
        int rw = rbase + mt * 16 + m;
        if (rw < NN) {
            int b0 = offR[rw], b1 = offR[rw + 1];
            for (int p = b0; p < b1; ++p) {
                int e = csrR[p];
                const unsigned short* bp = enew + (size_t)e * 128;
                short8 u0 = *(const short8*)(bp + q * 8);
                short8 u1 = *(const short8*)(bp + 32 + q * 8);
#pragma unroll
                for (int j = 0; j < 8; ++j) {
                    aggv[mt][j] += f_of_bf16((unsigned short)u0[j]);
                    aggv[mt][8 + j] += f_of_bf16((unsigned short)u1[j]);
                }
            }
            b0 = offS[rw]; b1 = offS[rw + 1];
            for (int p = b0; p < b1; ++p) {
                int e = csrS[p];
                const unsigned short* bp = enew + (size_t)e * 128 + 64;
                short8 u0 = *(const short8*)(bp + q * 8);
                short8 u1 = *(const short8*)(bp + 32 + q * 8);
#pragma unroll
                for (int j = 0; j < 8; ++j) {
                    aggv[mt][j] += f_of_bf16((unsigned short)u0[j]);
                    aggv[mt][8 + j] += f_of_bf16((unsigned short)u1[j]);
                }
            }
        }
    }

    int arow[2];
#pragma unroll
    for (int mt = 0; mt < 2; ++mt) {
        int rw = rbase + mt * 16 + m;
        arow[mt] = (rw < NN) ? rw : (NN - 1);
    }

    f32x4 acc0[8], acc1[8];
#pragma unroll
    for (int nt = 0; nt < 8; ++nt) { acc0[nt] = (f32x4)0.f; acc1[nt] = (f32x4)0.f; }

    // ---- MLP1: K=192 (6 chunks): 0..3 xb, 4..5 agg (registers)
#pragma unroll
    for (int c = 0; c < 6; ++c) {
        short8 af[2];
#pragma unroll
        for (int mt = 0; mt < 2; ++mt) {
            if (c < 4) {
                af[mt] = *(const short8*)(xb + (size_t)arow[mt] * 128 + c * 32 + q * 8);
            } else {
                short8 a;
#pragma unroll
                for (int j = 0; j < 8; ++j)
                    a[j] = (short)bf16_of(aggv[mt][(c - 4) * 8 + j]);
                af[mt] = a;
            }
        }
#pragma unroll
        for (int nt = 0; nt < 8; ++nt) {
            short8 bf = *(const short8*)(W1t + ((size_t)(nt * 16 + m)) * 192 + c * 32 + q * 8);
            acc0[nt] = __builtin_amdgcn_mfma_f32_16x16x32_bf16(af[0], bf, acc0[nt], 0, 0, 0);
            acc1[nt] = __builtin_amdgcn_mfma_f32_16x16x32_bf16(af[1], bf, acc1[nt], 0, 0, 0);
        }
    }
#pragma unroll
    for (int nt = 0; nt < 8; ++nt) {
        float bv = b1[nt * 16 + m];
#pragma unroll
        for (int r = 0; r < 4; ++r) {
            h[w][q * 4 + r][nt * 16 + m] = bf16_of(gelu_f(acc0[nt][r] + bv));
            h[w][16 + q * 4 + r][nt * 16 + m] = bf16_of(gelu_f(acc1[nt][r] + bv));
        }
        acc0[nt] = (f32x4)0.f;
        acc1[nt] = (f32x4)0.f;
    }
    // ---- MLP2
#pragma unroll
    for (int c = 0; c < 4; ++c) {
        short8 af0 = *(const short8*)&h[w][m][c * 32 + q * 8];
        short8 af1 = *(const short8*)&h[w][16 + m][c * 32 + q * 8];
#pragma unroll
        for (int nt = 0; nt < 8; ++nt) {
            short8 bf = *(const short8*)(W2t + ((size_t)(nt * 16 + m)) * 128 + c * 32 + q * 8);
            acc0[nt] = __builtin_amdgcn_mfma_f32_16x16x32_bf16(af0, bf, acc0[nt], 0, 0, 0);
            acc1[nt] = __builtin_amdgcn_mfma_f32_16x16x32_bf16(af1, bf, acc1[nt], 0, 0, 0);
        }
    }
#pragma unroll
    for (int nt = 0; nt < 8; ++nt) {
        float bv = b2[nt * 16 + m];
#pragma unroll
        for (int r = 0; r < 4; ++r) {
            h[w][q * 4 + r][nt * 16 + m] = bf16_of(gelu_f(acc0[nt][r] + bv));
            h[w][16 + q * 4 + r][nt * 16 + m] = bf16_of(gelu_f(acc1[nt][r] + bv));
        }
        acc0[nt] = (f32x4)0.f;
        acc1[nt] = (f32x4)0.f;
    }
    // ---- MLP3
#pragma unroll
    for (int c = 0; c < 4; ++c) {
        short8 af0 = *(const short8*)&h[w][m][c * 32 + q * 8];
        short8 af1 = *(const short8*)&h[w][16 + m][c * 32 + q * 8];
#pragma unroll
        for (int nt = 0; nt < 8; ++nt) {
            short8 bf = *(const short8*)(W3t + ((size_t)(nt * 16 + m)) * 128 + c * 32 + q * 8);
            acc0[nt] = __builtin_amdgcn_mfma_f32_16x16x32_bf16(af0, bf, acc0[nt], 0, 0, 0);
            acc1[nt] = __builtin_amdgcn_mfma_f32_16x16x32_bf16(af1, bf, acc1[nt], 0, 0, 0);
        }
    }
    // ---- epilogue
#pragma unroll
    for (int mt = 0; mt < 2; ++mt) {
        f32x4* acc = mt ? acc1 : acc0;
        float s[4] = {0.f, 0.f, 0.f, 0.f}, ss[4] = {0.f, 0.f, 0.f, 0.f};
#pragma unroll
        for (int nt = 0; nt < 8; ++nt) {
            float bv = b3[nt * 16 + m];
#pragma unroll
            for (int r = 0; r < 4; ++r) {
                float v = acc[nt][r] + bv;
                acc[nt][r] = v;
                s[r] += v;
                ss[r] += v * v;
            }
        }
#pragma unroll
        for (int r = 0; r < 4; ++r) {
#pragma unroll
            for (int msk = 1; msk < 16; msk <<= 1) {
                s[r] += __shfl_xor(s[r], msk, 64);
                ss[r] += __shfl_xor(ss[r], msk, 64);
            }
        }
#pragma unroll
        for (int r = 0; r < 4; ++r) {
            int row = rbase + mt * 16 + q * 4 + r;
            if (row < NN) {
                float mean = s[r] * (1.0f / 128.0f);
                float var = ss[r] * (1.0f / 128.0f) - mean * mean;
                float rstd = rsqrtf(var + 1e-5f);
#pragma unroll
                for (int nt = 0; nt < 8; ++nt) {
                    int col = nt * 16 + m;
                    float v = (acc[nt][r] - mean) * rstd * g[col] + beta[col];
                    size_t off = (size_t)row * 128 + col;
                    float res = xl[off] + v;
                    xl[off] = res;
                    xb[off] = bf16_of(res);
                }
            }
        }
    }
}

// ================= fp32 encoder / decoder (unchanged) =================
template <int KC>
static __device__ __forceinline__ void gemm_chunk(const float* A, int lda, const float* W,
                                                  int r0, int c0, float acc[4][4]) {
#pragma unroll
    for (int kk = 0; kk < KC; kk += 4) {
        float4 a[4];
        float4 w[4];
#pragma unroll
        for (int i = 0; i < 4; ++i) a[i] = *(const float4*)(A + (r0 + i) * lda + kk);
#pragma unroll
        for (int mm = 0; mm < 4; ++mm) w[mm] = *(const float4*)(W + (kk + mm) * 128 + c0);
#pragma unroll
        for (int i = 0; i < 4; ++i) {
            float am[4] = {a[i].x, a[i].y, a[i].z, a[i].w};
#pragma unroll
            for (int mm = 0; mm < 4; ++mm) {
                acc[i][0] = fmaf(am[mm], w[mm].x, acc[i][0]);
                acc[i][1] = fmaf(am[mm], w[mm].y, acc[i][1]);
                acc[i][2] = fmaf(am[mm], w[mm].z, acc[i][2]);
                acc[i][3] = fmaf(am[mm], w[mm].w, acc[i][3]);
            }
        }
    }
}

static __device__ __forceinline__ void bias_gelu_store(float acc[4][4], const float* __restrict__ b,
                                                       float* h, int r0, int c0) {
    float4 bb = *(const float4*)(b + c0);
    float bv[4] = {bb.x, bb.y, bb.z, bb.w};
#pragma unroll
    for (int i = 0; i < 4; ++i) {
        float4 o;
        o.x = gelu_f(acc[i][0] + bv[0]);
        o.y = gelu_f(acc[i][1] + bv[1]);
        o.z = gelu_f(acc[i][2] + bv[2]);
        o.w = gelu_f(acc[i][3] + bv[3]);
        *(float4*)(h + (r0 + i) * 128 + c0) = o;
#pragma unroll
        for (int j = 0; j < 4; ++j) acc[i][j] = 0.f;
    }
}

static __device__ __forceinline__ void ln_block(float acc[4][4], const float* __restrict__ b,
                                                const float* __restrict__ g,
                                                const float* __restrict__ beta, int c0,
                                                float vals[4][4]) {
    float4 bb = *(const float4*)(b + c0);
    float bv[4] = {bb.x, bb.y, bb.z, bb.w};
    float4 gg = *(const float4*)(g + c0);
    float gv[4] = {gg.x, gg.y, gg.z, gg.w};
    float4 bt = *(const float4*)(beta + c0);
    float btv[4] = {bt.x, bt.y, bt.z, bt.w};
#pragma unroll
    for (int i = 0; i < 4; ++i) {
        float v[4];
#pragma unroll
        for (int j = 0; j < 4; ++j) v[j] = acc[i][j] + bv[j];
        float sm = v[0] + v[1] + v[2] + v[3];
        float sq = v[0] * v[0] + v[1] * v[1] + v[2] * v[2] + v[3] * v[3];
#pragma unroll
        for (int mk = 1; mk < 32; mk <<= 1) {
            sm += __shfl_xor(sm, mk, 64);
            sq += __shfl_xor(sq, mk, 64);
        }
        float mean = sm * (1.0f / 128.0f);
        float var = sq * (1.0f / 128.0f) - mean * mean;
        float rstd = rsqrtf(var + 1e-5f);
#pragma unroll
        for (int j = 0; j < 4; ++j) vals[i][j] = (v[j] - mean) * rstd * gv[j] + btv[j];
    }
}

__global__ __launch_bounds__(256) void enc_kernel(
    const float* __restrict__ in, float* __restrict__ out,
    const float* __restrict__ W1, const float* __restrict__ b1,
    const float* __restrict__ W2, const float* __restrict__ b2,
    const float* __restrict__ W3, const float* __restrict__ b3,
    const float* __restrict__ g, const float* __restrict__ beta, int nrows) {
    __shared__ __align__(16) float Ast[32 * 16];
    __shared__ __align__(16) float Wt[32 * 128];
    __shared__ __align__(16) float h1[32 * 128];
    __shared__ __align__(16) float h2[32 * 128];
    int t = threadIdx.x;
    int tx = t & 31, ty = t >> 5;
    int r0 = ty * 4, c0 = tx * 4;
    int n0 = blockIdx.x * 32;

    if (t < 128) {
        int row = t >> 2, fc = t & 3;
        int rid = min(n0 + row, nrows - 1);
        *(float4*)(Ast + row * 16 + fc * 4) = *(const float4*)(in + (size_t)rid * 16 + fc * 4);
    }
    for (int qq = t; qq < 512; qq += 256)
        *(float4*)(Wt + qq * 4) = *(const float4*)(W1 + (size_t)qq * 4);
    __syncthreads();
    float acc[4][4] = {};
    gemm_chunk<16>(Ast, 16, Wt, r0, c0, acc);
    __syncthreads();
    bias_gelu_store(acc, b1, h1, r0, c0);
    for (int c = 0; c < 4; ++c) {
        for (int qq = t; qq < 1024; qq += 256)
            *(float4*)(Wt + qq * 4) = *(const float4*)(W2 + (size_t)c * 32 * 128 + qq * 4);
        __syncthreads();
        gemm_chunk<32>(h1 + c * 32, 128, Wt, r0, c0, acc);
        __syncthreads();
    }
    bias_gelu_store(acc, b2, h2, r0, c0);
    for (int c = 0; c < 4; ++c) {
        for (int qq = t; qq < 1024; qq += 256)
            *(float4*)(Wt + qq * 4) = *(const float4*)(W3 + (size_t)c * 32 * 128 + qq * 4);
        __syncthreads();
        gemm_chunk<32>(h2 + c * 32, 128, Wt, r0, c0, acc);
        __syncthreads();
    }
    float vals[4][4];
    ln_block(acc, b3, g, beta, c0, vals);
#pragma unroll
    for (int i = 0; i < 4; ++i) {
        int rid = n0 + r0 + i;
        if (rid < nrows) {
            float4 o = {vals[i][0], vals[i][1], vals[i][2], vals[i][3]};
            *(float4*)(out + (size_t)rid * 128 + c0) = o;
        }
    }
}

__global__ __launch_bounds__(256) void dec_kernel(
    const float* __restrict__ xl,
    const float* __restrict__ W1, const float* __restrict__ b1,
    const float* __restrict__ W2, const float* __restrict__ b2,
    const float* __restrict__ W3, const float* __restrict__ b3,
    float* __restrict__ out, int N_) {
    __shared__ __align__(16) float Ast[32 * 32];
    __shared__ __align__(16) float Wt[32 * 128];
    __shared__ __align__(16) float h1[32 * 128];
    __shared__ __align__(16) float h2[32 * 128];
    int t = threadIdx.x;
    int tx = t & 31, ty = t >> 5;
    int r0 = ty * 4, c0 = tx * 4;
    int n0 = blockIdx.x * 32;
    float acc[4][4] = {};
    for (int c = 0; c < 4; ++c) {
        {
            int row = t >> 3, fc = t & 7;
            int nid = min(n0 + row, N_ - 1);
            const float* src = xl + (size_t)nid * 128 + c * 32;
            *(float4*)(Ast + row * 32 + fc * 4) = *(const float4*)(src + fc * 4);
        }
        for (int qq = t; qq < 1024; qq += 256)
            *(float4*)(Wt + qq * 4) = *(const float4*)(W1 + (size_t)c * 32 * 128 + qq * 4);
        __syncthreads();
        gemm_chunk<32>(Ast, 32, Wt, r0, c0, acc);
        __syncthreads();
    }
    bias_gelu_store(acc, b1, h1, r0, c0);
    for (int c = 0; c < 4; ++c) {
        for (int qq = t; qq < 1024; qq += 256)
            *(float4*)(Wt + qq * 4) = *(const float4*)(W2 + (size_t)c * 32 * 128 + qq * 4);
        __syncthreads();
        gemm_chunk<32>(h1 + c * 32, 128, Wt, r0, c0, acc);
        __syncthreads();
    }
    bias_gelu_store(acc, b2, h2, r0, c0);
    __syncthreads();
    if (t < 96) {
        int r = t / 3, j = t - 3 * (t / 3);
        int nid = n0 + r;
        if (nid < N_) {
            float s = b3[j];
            for (int k = 0; k < 128; ++k) s = fmaf(h2[r * 128 + k], W3[k * 3 + j], s);
            out[(size_t)nid * 3 + j] = s;
        }
    }
}

static inline int cdiv(int a, int b) { return (a + b - 1) / b; }

extern "C" void kernel_launch(void* const* d_in, const int* in_sizes, int n_in,
                              void* d_out, int out_size, void* d_ws, size_t ws_size,
                              hipStream_t stream) {
    const float* x0 = (const float*)d_in[0];
    const float* ea0 = (const float*)d_in[1];
    const float* enW1 = (const float*)d_in[2];
    const float* enb1 = (const float*)d_in[3];
    const float* enW2 = (const float*)d_in[4];
    const float* enb2 = (const float*)d_in[5];
    const float* enW3 = (const float*)d_in[6];
    const float* enb3 = (const float*)d_in[7];
    const float* eng = (const float*)d_in[8];
    const float* enbt = (const float*)d_in[9];
    const float* eeW1 = (const float*)d_in[10];
    const float* eeb1 = (const float*)d_in[11];
    const float* eeW2 = (const float*)d_in[12];
    const float* eeb2 = (const float*)d_in[13];
    const float* eeW3 = (const float*)d_in[14];
    const float* eeb3 = (const float*)d_in[15];
    const float* eeg = (const float*)d_in[16];
    const float* eebt = (const float*)d_in[17];
    const float* beW1 = (const float*)d_in[18];
    const float* beb1 = (const float*)d_in[19];
    const float* beW2 = (const float*)d_in[20];
    const float* beb2 = (const float*)d_in[21];
    const float* beW3 = (const float*)d_in[22];
    const float* beb3 = (const float*)d_in[23];
    const float* beg = (const float*)d_in[24];
    const float* bebt = (const float*)d_in[25];
    const float* bnW1 = (const float*)d_in[26];
    const float* bnb1 = (const float*)d_in[27];
    const float* bnW2 = (const float*)d_in[28];
    const float* bnb2 = (const float*)d_in[29];
    const float* bnW3 = (const float*)d_in[30];
    const float* bnb3 = (const float*)d_in[31];
    const float* bng = (const float*)d_in[32];
    const float* bnbt = (const float*)d_in[33];
    const float* dW1 = (const float*)d_in[34];
    const float* db1 = (const float*)d_in[35];
    const float* dW2 = (const float*)d_in[36];
    const float* db2 = (const float*)d_in[37];
    const float* dW3 = (const float*)d_in[38];
    const float* db3 = (const float*)d_in[39];
    const int* ei = (const int*)d_in[40];
    const int* senders = ei;
    const int* receivers = ei + EE;

    // ---- workspace layout (all 16B-aligned)
    char* p = (char*)d_ws;
    float* xl = (float*)p;                     p += (size_t)NN * 128 * 4;
    float* el = (float*)p;                     p += (size_t)EE * 128 * 4;
    unsigned short* xb = (unsigned short*)p;   p += (size_t)NN * 128 * 2;
    unsigned short* enew = (unsigned short*)p; p += (size_t)EE * 128 * 2;
    unsigned short* ew1t = (unsigned short*)p; p += (size_t)LL * 128 * 384 * 2;
    unsigned short* ew2t = (unsigned short*)p; p += (size_t)LL * 128 * 128 * 2;
    unsigned short* ew3t = (unsigned short*)p; p += (size_t)LL * 128 * 128 * 2;
    unsigned short* nw1t = (unsigned short*)p; p += (size_t)LL * 128 * 192 * 2;
    unsigned short* nw2t = (unsigned short*)p; p += (size_t)LL * 128 * 128 * 2;
    unsigned short* nw3t = (unsigned short*)p; p += (size_t)LL * 128 * 128 * 2;
    int* cnt = (int*)p;                        p += (size_t)2 * NN * 4;   // cntR | cntS
    int* cur = (int*)p;                        p += (size_t)2 * NN * 4;   // curR | curS
    int* offR = (int*)p;                       p += (size_t)(NN + 4) * 4;
    int* offS = (int*)p;                       p += (size_t)(NN + 4) * 4;
    int* csrR = (int*)p;                       p += (size_t)EE * 4;
    int* csrS = (int*)p;                       p += (size_t)EE * 4;
    int* cntR = cnt, *cntS = cnt + NN;
    int* curR = cur, *curS = cur + NN;

    dim3 blk(256);
    // ---- weight convert+transpose (per launch)
    {
        int tot;
        tot = LL * 384 * 128;
        wt_t_kernel<<<cdiv(tot, 256), blk, 0, stream>>>(beW1, ew1t, 384, 128, tot);
        tot = LL * 128 * 128;
        wt_t_kernel<<<cdiv(tot, 256), blk, 0, stream>>>(beW2, ew2t, 128, 128, tot);
        wt_t_kernel<<<cdiv(tot, 256), blk, 0, stream>>>(beW3, ew3t, 128, 128, tot);
        wt_t_kernel<<<cdiv(tot, 256), blk, 0, stream>>>(bnW2, nw2t, 128, 128, tot);
        wt_t_kernel<<<cdiv(tot, 256), blk, 0, stream>>>(bnW3, nw3t, 128, 128, tot);
        tot = LL * 192 * 128;
        wt_t_kernel<<<cdiv(tot, 256), blk, 0, stream>>>(bnW1, nw1t, 192, 128, tot);
    }
    // ---- CSR build (once per launch, reused for all 15 layers)
    hipMemsetAsync(cnt, 0, (size_t)2 * NN * 4, stream);
    hist_kernel<<<cdiv(EE, 256), blk, 0, stream>>>(senders, receivers, cntR, cntS);
    scan_kernel<<<1, 1024, 0, stream>>>(cntR, cntS, offR, offS, curR, curS);
    fill_kernel<<<cdiv(EE, 256), blk, 0, stream>>>(senders, receivers, curR, curS, csrR, csrS);

    // ---- encoders (fp32) + bf16 node mirror
    enc_kernel<<<cdiv(NN, 32), blk, 0, stream>>>(x0, xl, enW1, enb1, enW2, enb2, enW3,
                                                 enb3, eng, enbt, NN);
    enc_kernel<<<cdiv(EE, 32), blk, 0, stream>>>(ea0, el, eeW1, eeb1, eeW2, eeb2, eeW3,
                                                 eeb3, eeg, eebt, EE);
    f2b_kernel<<<cdiv(NN * 32, 256), blk, 0, stream>>>(xl, xb, NN * 32);

    // ---- 15 message-passing layers
    for (int l = 0; l < LL; ++l) {
        edge_mfma_kernel<<<cdiv(EE, 128), blk, 0, stream>>>(
            xb, el, enew, senders, receivers,
            ew1t + (size_t)l * 128 * 384, beb1 + (size_t)l * 128,
            ew2t + (size_t)l * 128 * 128, beb2 + (size_t)l * 128,
            ew3t + (size_t)l * 128 * 128, beb3 + (size_t)l * 128,
            beg + (size_t)l * 128, bebt + (size_t)l * 128);
        node_mfma_kernel<<<cdiv(NN, 128), blk, 0, stream>>>(
            xl, xb, enew, offR, csrR, offS, csrS,
            nw1t + (size_t)l * 128 * 192, bnb1 + (size_t)l * 128,
            nw2t + (size_t)l * 128 * 128, bnb2 + (size_t)l * 128,
            nw3t + (size_t)l * 128 * 128, bnb3 + (size_t)l * 128,
            bng + (size_t)l * 128, bnbt + (size_t)l * 128);
    }
    // ---- decoder (fp32)
    dec_kernel<<<cdiv(NN, 32), blk, 0, stream>>>(xl, dW1, db1, dW2, db2, dW3, db3,
                                                 (float*)d_out, NN);
}

// Round 4
// 4261.082 us; speedup vs baseline: 2.2498x; 1.1801x over previous
//
#include <hip/hip_runtime.h>
#include <math.h>

// Problem constants (match reference setup_inputs)
#define NN 50000
#define EE 150000
#define LL 15

typedef __attribute__((ext_vector_type(8))) short short8;
typedef __attribute__((ext_vector_type(4))) float f32x4;

static __device__ __forceinline__ float gelu_f(float x) {
    return 0.5f * x * (1.0f + erff(x * 0.70710678118654752440f));
}

static __device__ __forceinline__ unsigned short bf16_of(float f) {
    union { float f; unsigned u; } v;
    v.f = f;
    unsigned r = (v.u + 0x7fffu + ((v.u >> 16) & 1u)) >> 16;  // RNE
    return (unsigned short)r;
}

static __device__ __forceinline__ float f_of_bf16(unsigned short u) {
    union { unsigned u; float f; } v;
    v.u = ((unsigned)u) << 16;
    return v.f;
}

// ---------------- weight transpose+convert+pad:
// in [C][K][N] fp32 -> out [C][Npad][Kpad] bf16 (zero-padded)
__global__ __launch_bounds__(256) void wt_t_kernel(const float* __restrict__ in,
                                                   unsigned short* __restrict__ out,
                                                   int K, int N, int Kpad, int Npad, int total) {
    int i = blockIdx.x * 256 + threadIdx.x;
    if (i >= total) return;
    int k = i % Kpad;
    int r = i / Kpad;
    int n = r % Npad;
    int c = r / Npad;
    out[i] = (k < K && n < N) ? bf16_of(in[((size_t)c * K + k) * N + n]) : (unsigned short)0;
}

// ---------------- CSR build: histogram
__global__ __launch_bounds__(256) void hist_kernel(const int* __restrict__ senders,
                                                   const int* __restrict__ receivers,
                                                   int* __restrict__ cntR, int* __restrict__ cntS) {
    int i = blockIdx.x * 256 + threadIdx.x;
    if (i >= EE) return;
    atomicAdd(&cntR[receivers[i]], 1);
    atomicAdd(&cntS[senders[i]], 1);
}

// ---------------- CSR build: bucket allocation (order-free; wave scan + 1 atomic/wave)
__global__ __launch_bounds__(256) void alloc_kernel(const int* __restrict__ cntR,
                                                    const int* __restrict__ cntS,
                                                    int* __restrict__ offR, int* __restrict__ offS,
                                                    int* __restrict__ curR, int* __restrict__ curS,
                                                    int* __restrict__ ctr) {
    int i = blockIdx.x * 256 + threadIdx.x;
    int lane = threadIdx.x & 63;
    int cR = (i < NN) ? cntR[i] : 0;
    int cS = (i < NN) ? cntS[i] : 0;
    int sR = cR, sS = cS;
#pragma unroll
    for (int d = 1; d < 64; d <<= 1) {
        int tR = __shfl_up(sR, d, 64);
        int tS = __shfl_up(sS, d, 64);
        if (lane >= d) { sR += tR; sS += tS; }
    }
    int baseR = 0, baseS = 0;
    if (lane == 63) {
        baseR = atomicAdd(&ctr[0], sR);
        baseS = atomicAdd(&ctr[1], sS);
    }
    baseR = __shfl(baseR, 63, 64);
    baseS = __shfl(baseS, 63, 64);
    if (i < NN) {
        int oR = baseR + sR - cR;
        offR[i] = oR; curR[i] = oR;
        int oS = baseS + sS - cS;
        offS[i] = oS; curS[i] = oS;
    }
}

// ---------------- CSR build: fill edge lists
__global__ __launch_bounds__(256) void fill_kernel(const int* __restrict__ senders,
                                                   const int* __restrict__ receivers,
                                                   int* __restrict__ curR, int* __restrict__ curS,
                                                   int* __restrict__ csrR, int* __restrict__ csrS) {
    int i = blockIdx.x * 256 + threadIdx.x;
    if (i >= EE) return;
    int pr = atomicAdd(&curR[receivers[i]], 1);
    csrR[pr] = i;
    int ps = atomicAdd(&curS[senders[i]], 1);
    csrS[ps] = i;
}

// ======== shared MFMA helpers ========
// h slab: per-wave private, rows stride 136 (bf16). A-frag: lane(m,q) holds
// A[m][k=q*8..+8]; B stored [n][k]; D: col=lane&15, row=q*4+reg.
template <int MT>
static __device__ __forceinline__ void mlp_from_h(const unsigned short* hb,
                                                  const unsigned short* __restrict__ Wt,
                                                  f32x4 acc[][8], int m, int q) {
#pragma unroll
    for (int c = 0; c < 4; ++c) {
        short8 af[MT];
#pragma unroll
        for (int mt = 0; mt < MT; ++mt)
            af[mt] = *(const short8*)(hb + (mt * 16 + m) * 136 + c * 32 + q * 8);
#pragma unroll
        for (int nt = 0; nt < 8; ++nt) {
            short8 bf = *(const short8*)(Wt + ((size_t)(nt * 16 + m)) * 128 + c * 32 + q * 8);
#pragma unroll
            for (int mt = 0; mt < MT; ++mt)
                acc[mt][nt] = __builtin_amdgcn_mfma_f32_16x16x32_bf16(af[mt], bf, acc[mt][nt], 0, 0, 0);
        }
    }
}

template <int MT>
static __device__ __forceinline__ void gelu_to_h(f32x4 acc[][8], const float* __restrict__ b,
                                                 unsigned short* hb, int m, int q) {
#pragma unroll
    for (int nt = 0; nt < 8; ++nt) {
        float bv = b[nt * 16 + m];
#pragma unroll
        for (int mt = 0; mt < MT; ++mt) {
#pragma unroll
            for (int r = 0; r < 4; ++r)
                hb[(mt * 16 + q * 4 + r) * 136 + nt * 16 + m] = bf16_of(gelu_f(acc[mt][nt][r] + bv));
            acc[mt][nt] = (f32x4)0.f;
        }
    }
}

// ================= MFMA edge block: 192 edges/block, 4 waves x 48 rows (3 m-tiles)
__global__ __launch_bounds__(256) void edge_mfma_kernel(
    const unsigned short* __restrict__ xb, float* __restrict__ el,
    unsigned short* __restrict__ enew,
    const int* __restrict__ senders, const int* __restrict__ receivers,
    const unsigned short* __restrict__ W1t, const float* __restrict__ b1,
    const unsigned short* __restrict__ W2t, const float* __restrict__ b2,
    const unsigned short* __restrict__ W3t, const float* __restrict__ b3,
    const float* __restrict__ g, const float* __restrict__ beta) {
    __shared__ __align__(16) unsigned short h[4][48][136];  // 52.2 KB
    int t = threadIdx.x;
    int w = t >> 6;
    int l = t & 63;
    int m = l & 15;
    int q = l >> 4;
    int rbase = blockIdx.x * 192 + w * 48;

    int arow[3], as[3], ar[3];
#pragma unroll
    for (int mt = 0; mt < 3; ++mt) {
        int rw = rbase + mt * 16 + m;
        if (rw >= EE) rw = EE - 1;
        arow[mt] = rw;
        as[mt] = senders[rw];
        ar[mt] = receivers[rw];
    }

    f32x4 acc[3][8];
#pragma unroll
    for (int mt = 0; mt < 3; ++mt)
#pragma unroll
        for (int nt = 0; nt < 8; ++nt) acc[mt][nt] = (f32x4)0.f;

    // ---- MLP1: K=384 (12 chunks): 0..3 x[sender], 4..7 x[receiver], 8..11 e (fp32->bf16)
#pragma unroll
    for (int c = 0; c < 12; ++c) {
        short8 af[3];
#pragma unroll
        for (int mt = 0; mt < 3; ++mt) {
            if (c < 4) {
                af[mt] = *(const short8*)(xb + (size_t)as[mt] * 128 + c * 32 + q * 8);
            } else if (c < 8) {
                af[mt] = *(const short8*)(xb + (size_t)ar[mt] * 128 + (c - 4) * 32 + q * 8);
            } else {
                const float* fp = el + (size_t)arow[mt] * 128 + (c - 8) * 32 + q * 8;
                float4 f0 = *(const float4*)fp;
                float4 f1 = *(const float4*)(fp + 4);
                short8 a;
                a[0] = (short)bf16_of(f0.x); a[1] = (short)bf16_of(f0.y);
                a[2] = (short)bf16_of(f0.z); a[3] = (short)bf16_of(f0.w);
                a[4] = (short)bf16_of(f1.x); a[5] = (short)bf16_of(f1.y);
                a[6] = (short)bf16_of(f1.z); a[7] = (short)bf16_of(f1.w);
                af[mt] = a;
            }
        }
#pragma unroll
        for (int nt = 0; nt < 8; ++nt) {
            short8 bf = *(const short8*)(W1t + ((size_t)(nt * 16 + m)) * 384 + c * 32 + q * 8);
#pragma unroll
            for (int mt = 0; mt < 3; ++mt)
                acc[mt][nt] = __builtin_amdgcn_mfma_f32_16x16x32_bf16(af[mt], bf, acc[mt][nt], 0, 0, 0);
        }
    }
    gelu_to_h<3>(acc, b1, &h[w][0][0], m, q);
    mlp_from_h<3>(&h[w][0][0], W2t, acc, m, q);
    gelu_to_h<3>(acc, b2, &h[w][0][0], m, q);
    mlp_from_h<3>(&h[w][0][0], W3t, acc, m, q);

    // ---- epilogue: bias, LN over 128, residual into el, e_new -> bf16
    float gv[8], btv[8];
#pragma unroll
    for (int nt = 0; nt < 8; ++nt) { gv[nt] = g[nt * 16 + m]; btv[nt] = beta[nt * 16 + m]; }
#pragma unroll
    for (int mt = 0; mt < 3; ++mt) {
        float s[4] = {0.f, 0.f, 0.f, 0.f}, ss[4] = {0.f, 0.f, 0.f, 0.f};
#pragma unroll
        for (int nt = 0; nt < 8; ++nt) {
            float bv = b3[nt * 16 + m];
#pragma unroll
            for (int r = 0; r < 4; ++r) {
                float v = acc[mt][nt][r] + bv;
                acc[mt][nt][r] = v;
                s[r] += v;
                ss[r] += v * v;
            }
        }
#pragma unroll
        for (int r = 0; r < 4; ++r) {
#pragma unroll
            for (int msk = 1; msk < 16; msk <<= 1) {
                s[r] += __shfl_xor(s[r], msk, 64);
                ss[r] += __shfl_xor(ss[r], msk, 64);
            }
        }
#pragma unroll
        for (int r = 0; r < 4; ++r) {
            int row = rbase + mt * 16 + q * 4 + r;
            if (row < EE) {
                float mean = s[r] * (1.0f / 128.0f);
                float var = ss[r] * (1.0f / 128.0f) - mean * mean;
                float rstd = rsqrtf(var + 1e-5f);
#pragma unroll
                for (int nt = 0; nt < 8; ++nt) {
                    int col = nt * 16 + m;
                    float v = (acc[mt][nt][r] - mean) * rstd * gv[nt] + btv[nt];
                    size_t off = (size_t)row * 128 + col;
                    el[off] = el[off] + v;
                    enew[off] = bf16_of(v);
                }
            }
        }
    }
}

// ================= MFMA node block: 128 nodes/block, 4 waves x 32 rows (2 m-tiles)
__global__ __launch_bounds__(256) void node_mfma_kernel(
    float* __restrict__ xl, unsigned short* __restrict__ xb,
    const unsigned short* __restrict__ enew,
    const int* __restrict__ offR, const int* __restrict__ cntR, const int* __restrict__ csrR,
    const int* __restrict__ offS, const int* __restrict__ cntS, const int* __restrict__ csrS,
    const unsigned short* __restrict__ W1t, const float* __restrict__ b1,
    const unsigned short* __restrict__ W2t, const float* __restrict__ b2,
    const unsigned short* __restrict__ W3t, const float* __restrict__ b3,
    const float* __restrict__ g, const float* __restrict__ beta) {
    __shared__ __align__(16) unsigned short h[4][32][136];
    int t = threadIdx.x;
    int w = t >> 6;
    int l = t & 63;
    int m = l & 15;
    int q = l >> 4;
    int rbase = blockIdx.x * 128 + w * 32;

    // ---- aggregation prologue (per-lane CSR gather, no atomics)
    float aggv[2][16];
#pragma unroll
    for (int mt = 0; mt < 2; ++mt)
#pragma unroll
        for (int j = 0; j < 16; ++j) aggv[mt][j] = 0.f;
#pragma unroll
    for (int mt = 0; mt < 2; ++mt) {
        int rw = rbase + mt * 16 + m;
        if (rw < NN) {
            int b0 = offR[rw], bn = b0 + cntR[rw];
            for (int p = b0; p < bn; ++p) {
                int e = csrR[p];
                const unsigned short* bp = enew + (size_t)e * 128;
                short8 u0 = *(const short8*)(bp + q * 8);
                short8 u1 = *(const short8*)(bp + 32 + q * 8);
#pragma unroll
                for (int j = 0; j < 8; ++j) {
                    aggv[mt][j] += f_of_bf16((unsigned short)u0[j]);
                    aggv[mt][8 + j] += f_of_bf16((unsigned short)u1[j]);
                }
            }
            b0 = offS[rw]; bn = b0 + cntS[rw];
            for (int p = b0; p < bn; ++p) {
                int e = csrS[p];
                const unsigned short* bp = enew + (size_t)e * 128 + 64;
                short8 u0 = *(const short8*)(bp + q * 8);
                short8 u1 = *(const short8*)(bp + 32 + q * 8);
#pragma unroll
                for (int j = 0; j < 8; ++j) {
                    aggv[mt][j] += f_of_bf16((unsigned short)u0[j]);
                    aggv[mt][8 + j] += f_of_bf16((unsigned short)u1[j]);
                }
            }
        }
    }

    int arow[2];
#pragma unroll
    for (int mt = 0; mt < 2; ++mt) {
        int rw = rbase + mt * 16 + m;
        arow[mt] = (rw < NN) ? rw : (NN - 1);
    }

    f32x4 acc[2][8];
#pragma unroll
    for (int mt = 0; mt < 2; ++mt)
#pragma unroll
        for (int nt = 0; nt < 8; ++nt) acc[mt][nt] = (f32x4)0.f;

    // ---- MLP1: K=192 (6 chunks): 0..3 xb, 4..5 agg (registers)
#pragma unroll
    for (int c = 0; c < 6; ++c) {
        short8 af[2];
#pragma unroll
        for (int mt = 0; mt < 2; ++mt) {
            if (c < 4) {
                af[mt] = *(const short8*)(xb + (size_t)arow[mt] * 128 + c * 32 + q * 8);
            } else {
                short8 a;
#pragma unroll
                for (int j = 0; j < 8; ++j)
                    a[j] = (short)bf16_of(aggv[mt][(c - 4) * 8 + j]);
                af[mt] = a;
            }
        }
#pragma unroll
        for (int nt = 0; nt < 8; ++nt) {
            short8 bf = *(const short8*)(W1t + ((size_t)(nt * 16 + m)) * 192 + c * 32 + q * 8);
#pragma unroll
            for (int mt = 0; mt < 2; ++mt)
                acc[mt][nt] = __builtin_amdgcn_mfma_f32_16x16x32_bf16(af[mt], bf, acc[mt][nt], 0, 0, 0);
        }
    }
    gelu_to_h<2>(acc, b1, &h[w][0][0], m, q);
    mlp_from_h<2>(&h[w][0][0], W2t, acc, m, q);
    gelu_to_h<2>(acc, b2, &h[w][0][0], m, q);
    mlp_from_h<2>(&h[w][0][0], W3t, acc, m, q);

    // ---- epilogue: LN, residual into xl, refresh xb mirror
    float gv[8], btv[8];
#pragma unroll
    for (int nt = 0; nt < 8; ++nt) { gv[nt] = g[nt * 16 + m]; btv[nt] = beta[nt * 16 + m]; }
#pragma unroll
    for (int mt = 0; mt < 2; ++mt) {
        float s[4] = {0.f, 0.f, 0.f, 0.f}, ss[4] = {0.f, 0.f, 0.f, 0.f};
#pragma unroll
        for (int nt = 0; nt < 8; ++nt) {
            float bv = b3[nt * 16 + m];
#pragma unroll
            for (int r = 0; r < 4; ++r) {
                float v = acc[mt][nt][r] + bv;
                acc[mt][nt][r] = v;
                s[r] += v;
                ss[r] += v * v;
            }
        }
#pragma unroll
        for (int r = 0; r < 4; ++r) {
#pragma unroll
            for (int msk = 1; msk < 16; msk <<= 1) {
                s[r] += __shfl_xor(s[r], msk, 64);
                ss[r] += __shfl_xor(ss[r], msk, 64);
            }
        }
#pragma unroll
        for (int r = 0; r < 4; ++r) {
            int row = rbase + mt * 16 + q * 4 + r;
            if (row < NN) {
                float mean = s[r] * (1.0f / 128.0f);
                float var = ss[r] * (1.0f / 128.0f) - mean * mean;
                float rstd = rsqrtf(var + 1e-5f);
#pragma unroll
                for (int nt = 0; nt < 8; ++nt) {
                    int col = nt * 16 + m;
                    float v = (acc[mt][nt][r] - mean) * rstd * gv[nt] + btv[nt];
                    size_t off = (size_t)row * 128 + col;
                    float res = xl[off] + v;
                    xl[off] = res;
                    xb[off] = bf16_of(res);
                }
            }
        }
    }
}

// ================= MFMA encoder: [rows,16] -> MLP(16->128->128->128) -> LN
// W1p is [128][32] (K zero-padded 16->32). outB optional bf16 mirror.
__global__ __launch_bounds__(256) void enc_mfma_kernel(
    const float* __restrict__ in,
    const unsigned short* __restrict__ W1p, const float* __restrict__ b1,
    const unsigned short* __restrict__ W2t, const float* __restrict__ b2,
    const unsigned short* __restrict__ W3t, const float* __restrict__ b3,
    const float* __restrict__ g, const float* __restrict__ beta,
    float* __restrict__ outF, unsigned short* __restrict__ outB, int nrows) {
    __shared__ __align__(16) unsigned short h[4][32][136];
    int t = threadIdx.x;
    int w = t >> 6;
    int l = t & 63;
    int m = l & 15;
    int q = l >> 4;
    int rbase = blockIdx.x * 128 + w * 32;

    int arow[2];
#pragma unroll
    for (int mt = 0; mt < 2; ++mt) {
        int rw = rbase + mt * 16 + m;
        arow[mt] = (rw < nrows) ? rw : (nrows - 1);
    }

    f32x4 acc[2][8];
#pragma unroll
    for (int mt = 0; mt < 2; ++mt)
#pragma unroll
        for (int nt = 0; nt < 8; ++nt) acc[mt][nt] = (f32x4)0.f;

    // ---- MLP1: single K=32 chunk (k>=16 zero)
    {
        short8 af[2];
#pragma unroll
        for (int mt = 0; mt < 2; ++mt) {
            short8 a = (short8)0;
            if (q < 2) {
                const float* fp = in + (size_t)arow[mt] * 16 + q * 8;
                float4 f0 = *(const float4*)fp;
                float4 f1 = *(const float4*)(fp + 4);
                a[0] = (short)bf16_of(f0.x); a[1] = (short)bf16_of(f0.y);
                a[2] = (short)bf16_of(f0.z); a[3] = (short)bf16_of(f0.w);
                a[4] = (short)bf16_of(f1.x); a[5] = (short)bf16_of(f1.y);
                a[6] = (short)bf16_of(f1.z); a[7] = (short)bf16_of(f1.w);
            }
            af[mt] = a;
        }
#pragma unroll
        for (int nt = 0; nt < 8; ++nt) {
            short8 bf = *(const short8*)(W1p + ((size_t)(nt * 16 + m)) * 32 + q * 8);
#pragma unroll
            for (int mt = 0; mt < 2; ++mt)
                acc[mt][nt] = __builtin_amdgcn_mfma_f32_16x16x32_bf16(af[mt], bf, acc[mt][nt], 0, 0, 0);
        }
    }
    gelu_to_h<2>(acc, b1, &h[w][0][0], m, q);
    mlp_from_h<2>(&h[w][0][0], W2t, acc, m, q);
    gelu_to_h<2>(acc, b2, &h[w][0][0], m, q);
    mlp_from_h<2>(&h[w][0][0], W3t, acc, m, q);

    float gv[8], btv[8];
#pragma unroll
    for (int nt = 0; nt < 8; ++nt) { gv[nt] = g[nt * 16 + m]; btv[nt] = beta[nt * 16 + m]; }
#pragma unroll
    for (int mt = 0; mt < 2; ++mt) {
        float s[4] = {0.f, 0.f, 0.f, 0.f}, ss[4] = {0.f, 0.f, 0.f, 0.f};
#pragma unroll
        for (int nt = 0; nt < 8; ++nt) {
            float bv = b3[nt * 16 + m];
#pragma unroll
            for (int r = 0; r < 4; ++r) {
                float v = acc[mt][nt][r] + bv;
                acc[mt][nt][r] = v;
                s[r] += v;
                ss[r] += v * v;
            }
        }
#pragma unroll
        for (int r = 0; r < 4; ++r) {
#pragma unroll
            for (int msk = 1; msk < 16; msk <<= 1) {
                s[r] += __shfl_xor(s[r], msk, 64);
                ss[r] += __shfl_xor(ss[r], msk, 64);
            }
        }
#pragma unroll
        for (int r = 0; r < 4; ++r) {
            int row = rbase + mt * 16 + q * 4 + r;
            if (row < nrows) {
                float mean = s[r] * (1.0f / 128.0f);
                float var = ss[r] * (1.0f / 128.0f) - mean * mean;
                float rstd = rsqrtf(var + 1e-5f);
#pragma unroll
                for (int nt = 0; nt < 8; ++nt) {
                    int col = nt * 16 + m;
                    float v = (acc[mt][nt][r] - mean) * rstd * gv[nt] + btv[nt];
                    size_t off = (size_t)row * 128 + col;
                    outF[off] = v;
                    if (outB) outB[off] = bf16_of(v);
                }
            }
        }
    }
}

// ================= MFMA decoder: xb -> MLP(128->128->128->3)
// W3p is [16][128] (N zero-padded 3->16).
__global__ __launch_bounds__(256) void dec_mfma_kernel(
    const unsigned short* __restrict__ xb,
    const unsigned short* __restrict__ W1t, const float* __restrict__ b1,
    const unsigned short* __restrict__ W2t, const float* __restrict__ b2,
    const unsigned short* __restrict__ W3p, const float* __restrict__ b3,
    float* __restrict__ out, int N_) {
    __shared__ __align__(16) unsigned short h[4][32][136];
    int t = threadIdx.x;
    int w = t >> 6;
    int l = t & 63;
    int m = l & 15;
    int q = l >> 4;
    int rbase = blockIdx.x * 128 + w * 32;

    int arow[2];
#pragma unroll
    for (int mt = 0; mt < 2; ++mt) {
        int rw = rbase + mt * 16 + m;
        arow[mt] = (rw < N_) ? rw : (N_ - 1);
    }

    f32x4 acc[2][8];
#pragma unroll
    for (int mt = 0; mt < 2; ++mt)
#pragma unroll
        for (int nt = 0; nt < 8; ++nt) acc[mt][nt] = (f32x4)0.f;

    // ---- MLP1: K=128 from xb
#pragma unroll
    for (int c = 0; c < 4; ++c) {
        short8 af[2];
#pragma unroll
        for (int mt = 0; mt < 2; ++mt)
            af[mt] = *(const short8*)(xb + (size_t)arow[mt] * 128 + c * 32 + q * 8);
#pragma unroll
        for (int nt = 0; nt < 8; ++nt) {
            short8 bf = *(const short8*)(W1t + ((size_t)(nt * 16 + m)) * 128 + c * 32 + q * 8);
#pragma unroll
            for (int mt = 0; mt < 2; ++mt)
                acc[mt][nt] = __builtin_amdgcn_mfma_f32_16x16x32_bf16(af[mt], bf, acc[mt][nt], 0, 0, 0);
        }
    }
    gelu_to_h<2>(acc, b1, &h[w][0][0], m, q);
    mlp_from_h<2>(&h[w][0][0], W2t, acc, m, q);
    gelu_to_h<2>(acc, b2, &h[w][0][0], m, q);

    // ---- final: 128 -> 3 (one padded n-tile)
    f32x4 a3[2];
    a3[0] = (f32x4)0.f;
    a3[1] = (f32x4)0.f;
#pragma unroll
    for (int c = 0; c < 4; ++c) {
        short8 bf = *(const short8*)(W3p + ((size_t)m) * 128 + c * 32 + q * 8);
#pragma unroll
        for (int mt = 0; mt < 2; ++mt) {
            short8 af = *(const short8*)(&h[w][0][0] + (mt * 16 + m) * 136 + c * 32 + q * 8);
            a3[mt] = __builtin_amdgcn_mfma_f32_16x16x32_bf16(af, bf, a3[mt], 0, 0, 0);
        }
    }
    if (m < 3) {
        float bv = b3[m];
#pragma unroll
        for (int mt = 0; mt < 2; ++mt) {
#pragma unroll
            for (int r = 0; r < 4; ++r) {
                int row = rbase + mt * 16 + q * 4 + r;
                if (row < N_) out[(size_t)row * 3 + m] = a3[mt][r] + bv;
            }
        }
    }
}

static inline int cdiv(int a, int b) { return (a + b - 1) / b; }

extern "C" void kernel_launch(void* const* d_in, const int* in_sizes, int n_in,
                              void* d_out, int out_size, void* d_ws, size_t ws_size,
                              hipStream_t stream) {
    const float* x0 = (const float*)d_in[0];
    const float* ea0 = (const float*)d_in[1];
    const float* enW1 = (const float*)d_in[2];
    const float* enb1 = (const float*)d_in[3];
    const float* enW2 = (const float*)d_in[4];
    const float* enb2 = (const float*)d_in[5];
    const float* enW3 = (const float*)d_in[6];
    const float* enb3 = (const float*)d_in[7];
    const float* eng = (const float*)d_in[8];
    const float* enbt = (const float*)d_in[9];
    const float* eeW1 = (const float*)d_in[10];
    const float* eeb1 = (const float*)d_in[11];
    const float* eeW2 = (const float*)d_in[12];
    const float* eeb2 = (const float*)d_in[13];
    const float* eeW3 = (const float*)d_in[14];
    const float* eeb3 = (const float*)d_in[15];
    const float* eeg = (const float*)d_in[16];
    const float* eebt = (const float*)d_in[17];
    const float* beW1 = (const float*)d_in[18];
    const float* beb1 = (const float*)d_in[19];
    const float* beW2 = (const float*)d_in[20];
    const float* beb2 = (const float*)d_in[21];
    const float* beW3 = (const float*)d_in[22];
    const float* beb3 = (const float*)d_in[23];
    const float* beg = (const float*)d_in[24];
    const float* bebt = (const float*)d_in[25];
    const float* bnW1 = (const float*)d_in[26];
    const float* bnb1 = (const float*)d_in[27];
    const float* bnW2 = (const float*)d_in[28];
    const float* bnb2 = (const float*)d_in[29];
    const float* bnW3 = (const float*)d_in[30];
    const float* bnb3 = (const float*)d_in[31];
    const float* bng = (const float*)d_in[32];
    const float* bnbt = (const float*)d_in[33];
    const float* dW1 = (const float*)d_in[34];
    const float* db1 = (const float*)d_in[35];
    const float* dW2 = (const float*)d_in[36];
    const float* db2 = (const float*)d_in[37];
    const float* dW3 = (const float*)d_in[38];
    const float* db3 = (const float*)d_in[39];
    const int* ei = (const int*)d_in[40];
    const int* senders = ei;
    const int* receivers = ei + EE;

    // ---- workspace layout (all 16B-aligned)
    char* p = (char*)d_ws;
    float* xl = (float*)p;                     p += (size_t)NN * 128 * 4;
    float* el = (float*)p;                     p += (size_t)EE * 128 * 4;
    unsigned short* xb = (unsigned short*)p;   p += (size_t)NN * 128 * 2;
    unsigned short* enew = (unsigned short*)p; p += (size_t)EE * 128 * 2;
    unsigned short* ew1t = (unsigned short*)p; p += (size_t)LL * 128 * 384 * 2;
    unsigned short* ew2t = (unsigned short*)p; p += (size_t)LL * 128 * 128 * 2;
    unsigned short* ew3t = (unsigned short*)p; p += (size_t)LL * 128 * 128 * 2;
    unsigned short* nw1t = (unsigned short*)p; p += (size_t)LL * 128 * 192 * 2;
    unsigned short* nw2t = (unsigned short*)p; p += (size_t)LL * 128 * 128 * 2;
    unsigned short* nw3t = (unsigned short*)p; p += (size_t)LL * 128 * 128 * 2;
    unsigned short* enw1p = (unsigned short*)p; p += (size_t)128 * 32 * 2;
    unsigned short* enw2t = (unsigned short*)p; p += (size_t)128 * 128 * 2;
    unsigned short* enw3t = (unsigned short*)p; p += (size_t)128 * 128 * 2;
    unsigned short* eew1p = (unsigned short*)p; p += (size_t)128 * 32 * 2;
    unsigned short* eew2t = (unsigned short*)p; p += (size_t)128 * 128 * 2;
    unsigned short* eew3t = (unsigned short*)p; p += (size_t)128 * 128 * 2;
    unsigned short* dw1t = (unsigned short*)p;  p += (size_t)128 * 128 * 2;
    unsigned short* dw2t = (unsigned short*)p;  p += (size_t)128 * 128 * 2;
    unsigned short* dw3p = (unsigned short*)p;  p += (size_t)16 * 128 * 2;
    int* cnt = (int*)p;                        p += (size_t)2 * NN * 4;   // cntR | cntS
    int* ctr = (int*)p;                        p += 16;                   // 2 counters
    int* cur = (int*)p;                        p += (size_t)2 * NN * 4;   // curR | curS
    int* offR = (int*)p;                       p += (size_t)(NN + 4) * 4;
    int* offS = (int*)p;                       p += (size_t)(NN + 4) * 4;
    int* csrR = (int*)p;                       p += (size_t)EE * 4;
    int* csrS = (int*)p;                       p += (size_t)EE * 4;
    int* cntR = cnt, *cntS = cnt + NN;
    int* curR = cur, *curS = cur + NN;

    dim3 blk(256);
    // ---- weight convert+transpose (per launch)
    {
        int tot;
        tot = LL * 128 * 384;
        wt_t_kernel<<<cdiv(tot, 256), blk, 0, stream>>>(beW1, ew1t, 384, 128, 384, 128, tot);
        tot = LL * 128 * 128;
        wt_t_kernel<<<cdiv(tot, 256), blk, 0, stream>>>(beW2, ew2t, 128, 128, 128, 128, tot);
        wt_t_kernel<<<cdiv(tot, 256), blk, 0, stream>>>(beW3, ew3t, 128, 128, 128, 128, tot);
        wt_t_kernel<<<cdiv(tot, 256), blk, 0, stream>>>(bnW2, nw2t, 128, 128, 128, 128, tot);
        wt_t_kernel<<<cdiv(tot, 256), blk, 0, stream>>>(bnW3, nw3t, 128, 128, 128, 128, tot);
        tot = LL * 128 * 192;
        wt_t_kernel<<<cdiv(tot, 256), blk, 0, stream>>>(bnW1, nw1t, 192, 128, 192, 128, tot);
        tot = 128 * 32;
        wt_t_kernel<<<cdiv(tot, 256), blk, 0, stream>>>(enW1, enw1p, 16, 128, 32, 128, tot);
        wt_t_kernel<<<cdiv(tot, 256), blk, 0, stream>>>(eeW1, eew1p, 16, 128, 32, 128, tot);
        tot = 128 * 128;
        wt_t_kernel<<<cdiv(tot, 256), blk, 0, stream>>>(enW2, enw2t, 128, 128, 128, 128, tot);
        wt_t_kernel<<<cdiv(tot, 256), blk, 0, stream>>>(enW3, enw3t, 128, 128, 128, 128, tot);
        wt_t_kernel<<<cdiv(tot, 256), blk, 0, stream>>>(eeW2, eew2t, 128, 128, 128, 128, tot);
        wt_t_kernel<<<cdiv(tot, 256), blk, 0, stream>>>(eeW3, eew3t, 128, 128, 128, 128, tot);
        wt_t_kernel<<<cdiv(tot, 256), blk, 0, stream>>>(dW1, dw1t, 128, 128, 128, 128, tot);
        wt_t_kernel<<<cdiv(tot, 256), blk, 0, stream>>>(dW2, dw2t, 128, 128, 128, 128, tot);
        tot = 16 * 128;
        wt_t_kernel<<<cdiv(tot, 256), blk, 0, stream>>>(dW3, dw3p, 128, 3, 128, 16, tot);
    }
    // ---- CSR build (once per launch; bucket order arbitrary)
    hipMemsetAsync(cnt, 0, (size_t)2 * NN * 4 + 16, stream);
    hist_kernel<<<cdiv(EE, 256), blk, 0, stream>>>(senders, receivers, cntR, cntS);
    alloc_kernel<<<cdiv(NN, 256), blk, 0, stream>>>(cntR, cntS, offR, offS, curR, curS, ctr);
    fill_kernel<<<cdiv(EE, 256), blk, 0, stream>>>(senders, receivers, curR, curS, csrR, csrS);

    // ---- encoders (MFMA)
    enc_mfma_kernel<<<cdiv(NN, 128), blk, 0, stream>>>(x0, enw1p, enb1, enw2t, enb2,
                                                       enw3t, enb3, eng, enbt, xl, xb, NN);
    enc_mfma_kernel<<<cdiv(EE, 128), blk, 0, stream>>>(ea0, eew1p, eeb1, eew2t, eeb2,
                                                       eew3t, eeb3, eeg, eebt, el,
                                                       (unsigned short*)nullptr, EE);

    // ---- 15 message-passing layers
    for (int l = 0; l < LL; ++l) {
        edge_mfma_kernel<<<cdiv(EE, 192), blk, 0, stream>>>(
            xb, el, enew, senders, receivers,
            ew1t + (size_t)l * 128 * 384, beb1 + (size_t)l * 128,
            ew2t + (size_t)l * 128 * 128, beb2 + (size_t)l * 128,
            ew3t + (size_t)l * 128 * 128, beb3 + (size_t)l * 128,
            beg + (size_t)l * 128, bebt + (size_t)l * 128);
        node_mfma_kernel<<<cdiv(NN, 128), blk, 0, stream>>>(
            xl, xb, enew, offR, cntR, csrR, offS, cntS, csrS,
            nw1t + (size_t)l * 128 * 192, bnb1 + (size_t)l * 128,
            nw2t + (size_t)l * 128 * 128, bnb2 + (size_t)l * 128,
            nw3t + (size_t)l * 128 * 128, bnb3 + (size_t)l * 128,
            bng + (size_t)l * 128, bnbt + (size_t)l * 128);
    }
    // ---- decoder (MFMA)
    dec_mfma_kernel<<<cdiv(NN, 128), blk, 0, stream>>>(xb, dw1t, db1, dw2t, db2,
                                                       dw3p, db3, (float*)d_out, NN);
}